// Round 9
// baseline (3135.823 us; speedup 1.0000x reference)
//
#include <hip/hip_runtime.h>
#include <hip/hip_bf16.h>

typedef unsigned short u16;
typedef __attribute__((ext_vector_type(8))) short bf16x8;
typedef __attribute__((ext_vector_type(4))) float f32x4;
typedef __attribute__((ext_vector_type(4))) unsigned u32x4;

static constexpr int V = 20000, H = 400, B = 16, S = 256, NSLOT = 30, T = 10, G = 3;
static constexpr int H3 = 3 * H;           // 1200
static constexpr int NB = NSLOT * B;       // 480
// encoder partition
static constexpr int ENBLK = 20;           // blocks per direction
static constexpr int ESL   = 20;           // h components per block (400/20)
static constexpr int EROWS = 64;           // padded weight rows per block (4 waves x 16)
static constexpr int EKP   = 416;          // padded K
static constexpr int NFLG  = 4 * ENBLK;    // 80 per-wave flags per (dir, step)
// fused decoder LDS strides
static constexpr int HP2 = 424;            // h_lds row stride (u16)
static constexpr int SCP = 260;            // scores row stride (f32)
static constexpr int PP  = 264;            // prob row stride (u16)
static constexpr int CXP = 404;            // ctx row stride (f32)
static constexpr int FUSED_LDS = 32*HP2*2 + 32*SCP*4 + 32*PP*2 + 32*CXP*4; // 129024

__device__ __forceinline__ float bf2f(u16 v) {
    union { unsigned u; float f; } x; x.u = ((unsigned)v) << 16; return x.f;
}
__device__ __forceinline__ u16 f2bf(float f) {
    union { float f; unsigned u; } x; x.f = f;
    unsigned r = x.u + 0x7fffu + ((x.u >> 16) & 1u);   // round-to-nearest-even
    return (u16)(r >> 16);
}
__device__ __forceinline__ float sigm(float v) { return 1.f / (1.f + __expf(-v)); }

// ---------------------------------------------------------------------------
// Generic batched GEMM: C[m][n] = sum_k A[m][k] * Bt[n][k]  (+bias[n])
// mode 0: plain (+bias). mode 1: C=exp(acc)+rowsum, ldc layout.
// mode 2: C=exp(acc)+rowsum, vocab layout: row=t*NB+n -> C[((n*T)+t)*V + col].
// ---------------------------------------------------------------------------
__global__ __launch_bounds__(256) void gemm_bt(
    const u16* __restrict__ A, const u16* __restrict__ Bt,
    const float* __restrict__ bias, float* __restrict__ C,
    int M, int N, int K, int lda, int ldb, long long ldc,
    long long sA, long long sB, long long sC,
    int mode, float* __restrict__ rowsum)
{
    __shared__ u16 As[64][40];
    __shared__ u16 Bs[64][40];
    const int bz = blockIdx.z;
    A  += (long long)bz * sA;
    Bt += (long long)bz * sB;
    C  += (long long)bz * sC;
    const int m0 = blockIdx.x * 64, n0 = blockIdx.y * 64;
    const int tid = threadIdx.x, wave = tid >> 6, lane = tid & 63;
    const int wm = (wave >> 1) * 32, wn = (wave & 1) * 32;
    const int srow = tid >> 2, scol = (tid & 3) * 8;
    const int fr = lane & 15, kq = lane >> 4;
    f32x4 acc[2][2];
#pragma unroll
    for (int i = 0; i < 2; ++i)
#pragma unroll
        for (int j = 0; j < 2; ++j) acc[i][j] = (f32x4){0.f, 0.f, 0.f, 0.f};

    for (int k0 = 0; k0 < K; k0 += 32) {
        {
            int gr = m0 + srow, gc = k0 + scol;
            bf16x8 v;
            if (gr < M && gc + 8 <= K) {
                v = *(const bf16x8*)(A + (long long)gr * lda + gc);
            } else {
                short tmp[8];
#pragma unroll
                for (int j = 0; j < 8; ++j)
                    tmp[j] = (gr < M && gc + j < K) ? (short)A[(long long)gr * lda + gc + j] : (short)0;
                v = *(bf16x8*)tmp;
            }
            *(bf16x8*)&As[srow][scol] = v;
        }
        {
            int gr = n0 + srow, gc = k0 + scol;
            bf16x8 v;
            if (gr < N && gc + 8 <= K) {
                v = *(const bf16x8*)(Bt + (long long)gr * ldb + gc);
            } else {
                short tmp[8];
#pragma unroll
                for (int j = 0; j < 8; ++j)
                    tmp[j] = (gr < N && gc + j < K) ? (short)Bt[(long long)gr * ldb + gc + j] : (short)0;
                v = *(bf16x8*)tmp;
            }
            *(bf16x8*)&Bs[srow][scol] = v;
        }
        __syncthreads();
        bf16x8 af[2], bfr[2];
#pragma unroll
        for (int i = 0; i < 2; ++i) af[i]  = *(const bf16x8*)&As[wm + i * 16 + fr][kq * 8];
#pragma unroll
        for (int j = 0; j < 2; ++j) bfr[j] = *(const bf16x8*)&Bs[wn + j * 16 + fr][kq * 8];
#pragma unroll
        for (int i = 0; i < 2; ++i)
#pragma unroll
            for (int j = 0; j < 2; ++j)
                acc[i][j] = __builtin_amdgcn_mfma_f32_16x16x32_bf16(af[i], bfr[j], acc[i][j], 0, 0, 0);
        __syncthreads();
    }

#pragma unroll
    for (int i = 0; i < 2; ++i)
#pragma unroll
        for (int j = 0; j < 2; ++j) {
            int col = n0 + wn + j * 16 + fr;
            float bv = (bias != nullptr && col < N) ? bias[col] : 0.f;
#pragma unroll
            for (int r = 0; r < 4; ++r) {
                int row = m0 + wm + i * 16 + kq * 4 + r;
                bool ok = (row < M) && (col < N);
                float v = acc[i][j][r] + bv;
                if (mode >= 1) { v = ok ? __expf(v) : 0.f; acc[i][j][r] = v; }
                if (ok) {
                    long long coff;
                    if (mode == 2)
                        coff = ((long long)(row % NB) * T + (row / NB)) * (long long)V + col;
                    else
                        coff = (long long)row * ldc + col;
                    C[coff] = v;
                }
            }
        }
    if (mode >= 1) {
#pragma unroll
        for (int i = 0; i < 2; ++i)
#pragma unroll
            for (int r = 0; r < 4; ++r) {
                float s = acc[i][0][r] + acc[i][1][r];
                s += __shfl_xor(s, 1); s += __shfl_xor(s, 2);
                s += __shfl_xor(s, 4); s += __shfl_xor(s, 8);
                if (fr == 0) {
                    int row = m0 + wm + i * 16 + kq * 4 + r;
                    if (row < M) atomicAdd(&rowsum[row], s);
                }
            }
    }
}

// ---------------------------------------------------------------------------
// small utility kernels
// ---------------------------------------------------------------------------
__global__ void cvt_bf16_kernel(const float* __restrict__ src, u16* __restrict__ dst, int n) {
    for (int i = blockIdx.x * blockDim.x + threadIdx.x; i < n; i += gridDim.x * blockDim.x)
        dst[i] = f2bf(src[i]);
}

__global__ void cvt4_kernel(const float* __restrict__ a, const float* __restrict__ b,
                            const float* __restrict__ c, const float* __restrict__ d,
                            u16* __restrict__ da, u16* __restrict__ db,
                            u16* __restrict__ dc, u16* __restrict__ dd, int n) {
    for (int i = blockIdx.x * blockDim.x + threadIdx.x; i < n; i += gridDim.x * blockDim.x) {
        da[i] = f2bf(a[i]); db[i] = f2bf(b[i]); dc[i] = f2bf(c[i]); dd[i] = f2bf(d[i]);
    }
}

// weight prep, wave-local layout: dst[dir][j][w][m][k], m in [0,16):
//   m<15: g=m/5 (r/z/n), comp c = w*5 + m%5 -> src row g*H + j*ESL + c
//   m==15: zero pad row
__global__ void prep_wenc_kernel(const float* __restrict__ whhf, const float* __restrict__ whhb,
                                 u16* __restrict__ dst) {
    int idx = blockIdx.x * 256 + threadIdx.x;
    const int total = 2 * ENBLK * EROWS * EKP;
    if (idx >= total) return;
    int k = idx % EKP; int r = idx / EKP;
    int rloc = r % EROWS; r /= EROWS;
    int j = r % ENBLK; int dir = r / ENBLK;
    int w = rloc >> 4, m = rloc & 15;
    u16 v = 0;
    if (k < H && m < 15) {
        int g = m / 5, cc = m % 5;
        const float* W = dir ? whhb : whhf;
        v = f2bf(W[(long long)(g * H + j * ESL + w * 5 + cc) * H + k]);
    }
    dst[idx] = v;
}

__global__ void embed_story_kernel(const int* __restrict__ story, const u16* __restrict__ embb,
                                   u16* __restrict__ xb) {
    int row = blockIdx.x;                 // row = s*16 + b
    int s = row >> 4, b = row & 15;
    int tok = story[b * S + s];
    const u16* e = embb + (long long)tok * H;
    u16* d = xb + (long long)row * H;
    for (int k = threadIdx.x; k < H; k += blockDim.x) d[k] = e[k];
}

__global__ void build_decin_kernel(const int* __restrict__ tgt, const int* __restrict__ dom,
                                   const int* __restrict__ sidx, const float* __restrict__ slt,
                                   const u16* __restrict__ embb, u16* __restrict__ decin) {
    int n = blockIdx.x, t = blockIdx.y;
    int b = n & 15, slot = n >> 4;
    u16* d = decin + ((long long)t * NB + n) * H;
    if (t == 0) {
        const float* s1 = slt + (long long)dom[slot] * H;
        const float* s2 = slt + (long long)sidx[slot] * H;
        for (int k = threadIdx.x; k < H; k += blockDim.x) d[k] = f2bf(s1[k] + s2[k]);
    } else {
        int tok = tgt[(b * NSLOT + slot) * T + (t - 1)];
        const u16* e = embb + (long long)tok * H;
        for (int k = threadIdx.x; k < H; k += blockDim.x) d[k] = e[k];
    }
}

// ---------------------------------------------------------------------------
// Distributed encoder recurrence — protocol v7 (BARRIER-FREE, wave-sync):
//  - wave w of block j owns components c = j*20 + w*5 + [0,5): its 16 MFMA
//    rows are [r0..r4, z0..z4, n0..n4, pad] -> D-frag handoff to the GRU cell
//    stays INSIDE the wave (own ghs region, same-wave LDS FIFO order).
//  - weights staged per-wave; NO __syncthreads anywhere in the kernel.
//  - publish: relaxed agent (sc1 write-through) stores; per-wave inline
//    s_waitcnt vmcnt(0); per-wave rotating flag (80 per dir,step, store-only).
//  - readers poll 80 flags relaxed (2 loads/lane), then plain dwordx4 reads
//    of the rotating hbuf region (L2-cold -> L3-fresh). No fences at all.
// ---------------------------------------------------------------------------
__global__ __launch_bounds__(256) void enc_rnn_bf_kernel(
    const u16* __restrict__ wencp,
    const float* __restrict__ bhhf, const float* __restrict__ bhhb,
    const float* __restrict__ gif, const float* __restrict__ gib,
    const int* __restrict__ lens,
    unsigned* __restrict__ hbuf, int* __restrict__ flags,
    float* __restrict__ ysf, float* __restrict__ ysb,
    float* __restrict__ hfo, float* __restrict__ hbo)
{
    const int bid = blockIdx.x;
    const int dir = bid / ENBLK, j = bid % ENBLK;
    const float* bhh = dir ? bhhb : bhhf;
    const float* gi  = dir ? gib  : gif;
    float* ys = dir ? ysb : ysf;
    float* ho = dir ? hbo : hfo;

    __shared__ u16 wlds[EROWS * EKP];      // 53248 B, [wave][16][EKP]
    __shared__ float ghs[4][16 * 17];      // 4352 B, per-wave D regions

    const int tid = threadIdx.x, w = tid >> 6, lane = tid & 63;
    const int fr = lane & 15, kq = lane >> 4;

    // wave-local weight staging (each wave stages only its own 16 rows)
    const u16* wsrc = wencp + (long long)(dir * ENBLK + j) * EROWS * EKP;
    for (int i = lane * 8; i < 16 * EKP; i += 64 * 8)
        *(bf16x8*)&wlds[w * 16 * EKP + i] = *(const bf16x8*)&wsrc[w * 16 * EKP + i];

    // pair ownership: (b=fr, c=kq); kq==0 lanes also own (b=fr, c=4)
    const int b = fr;
    const int k0g = j * ESL + w * 5 + kq;       // pair0 global component
    const bool has1 = (kq == 0);
    const int k1g = j * ESL + w * 5 + 4;        // pair1 (kq==0 only)
    const int len = lens[b];
    const float bhr0 = bhh[k0g], bhz0 = bhh[H + k0g], bhn0 = bhh[2 * H + k0g];
    const float bhr1 = has1 ? bhh[k1g] : 0.f;
    const float bhz1 = has1 ? bhh[H + k1g] : 0.f;
    const float bhn1 = has1 ? bhh[2 * H + k1g] : 0.f;
    float h0r = 0.f, h1r = 0.f;

    unsigned* hb_d = hbuf + (long long)dir * S * B * EKP;
    int* flg_d = flags + dir * S * NFLG;
    const u16* arow = &wlds[(w * 16 + fr) * EKP + kq * 8];
    float* ghw = ghs[w];

    for (int t = 0; t < S; ++t) {
        const int s = dir ? (S - 1 - t) : t;
        const float* gbase = gi + (long long)s * B * H3;
        float gr0 = gbase[b * H3 + k0g];
        float gz0 = gbase[b * H3 + H + k0g];
        float gn0 = gbase[b * H3 + 2 * H + k0g];
        float gr1 = 0.f, gz1 = 0.f, gn1 = 0.f;
        if (has1) {
            gr1 = gbase[b * H3 + k1g];
            gz1 = gbase[b * H3 + H + k1g];
            gn1 = gbase[b * H3 + 2 * H + k1g];
        }

        f32x4 acc = (f32x4){0.f, 0.f, 0.f, 0.f};
        if (t > 0) {
            // relaxed sc1 spin over the 80 per-wave flags of step t-1
            const int* fl = flg_d + (t - 1) * NFLG;
            for (;;) {
                int v1 = __hip_atomic_load(&fl[lane], __ATOMIC_RELAXED,
                                           __HIP_MEMORY_SCOPE_AGENT);
                int v2 = __hip_atomic_load(&fl[16 + lane], __ATOMIC_RELAXED,
                                           __HIP_MEMORY_SCOPE_AGENT);
                if (__all(v1 != 0 && v2 != 0)) break;
                __builtin_amdgcn_s_sleep(2);
            }
            asm volatile("" ::: "memory");   // keep hbuf reads after the poll
            const unsigned* hrow = hb_d + ((long long)(t - 1) * B + fr) * EKP + kq * 8;
            f32x4 acch = (f32x4){0.f, 0.f, 0.f, 0.f};
            f32x4 accl = (f32x4){0.f, 0.f, 0.f, 0.f};
#pragma unroll
            for (int kk = 0; kk < 13; ++kk) {
                u32x4 a = *(const u32x4*)(hrow + kk * 32);
                u32x4 c = *(const u32x4*)(hrow + kk * 32 + 4);
                union { unsigned u[4]; bf16x8 v; } hi, lo;
                hi.u[0] = __builtin_amdgcn_perm(a[1], a[0], 0x05040100u);
                hi.u[1] = __builtin_amdgcn_perm(a[3], a[2], 0x05040100u);
                hi.u[2] = __builtin_amdgcn_perm(c[1], c[0], 0x05040100u);
                hi.u[3] = __builtin_amdgcn_perm(c[3], c[2], 0x05040100u);
                lo.u[0] = __builtin_amdgcn_perm(a[1], a[0], 0x07060302u);
                lo.u[1] = __builtin_amdgcn_perm(a[3], a[2], 0x07060302u);
                lo.u[2] = __builtin_amdgcn_perm(c[1], c[0], 0x07060302u);
                lo.u[3] = __builtin_amdgcn_perm(c[3], c[2], 0x07060302u);
                bf16x8 av = *(const bf16x8*)(arow + kk * 32);
                acch = __builtin_amdgcn_mfma_f32_16x16x32_bf16(av, hi.v, acch, 0, 0, 0);
                accl = __builtin_amdgcn_mfma_f32_16x16x32_bf16(av, lo.v, accl, 0, 0, 0);
            }
            acc = acch + accl;
        }
        // D -> own wave's ghs region (rows kq*4..kq*4+3, col fr)
#pragma unroll
        for (int r = 0; r < 4; ++r) ghw[(kq * 4 + r) * 17 + fr] = acc[r];
        __builtin_amdgcn_wave_barrier();   // compiler reorder guard (no-op)

        unsigned* hpub = hb_d + (long long)t * B * EKP;
        {   // cell pair0: component c=kq (rows kq, 5+kq, 10+kq of own region)
            float ghr = ghw[kq * 17 + b];
            float ghz = ghw[(5 + kq) * 17 + b];
            float ghn = ghw[(10 + kq) * 17 + b];
            float rg = sigm(gr0 + ghr + bhr0);
            float zg = sigm(gz0 + ghz + bhz0);
            float ng = tanhf(gn0 + rg * (ghn + bhn0));
            float hn = (1.f - zg) * ng + zg * h0r;
            bool msk = s < len;
            float y = msk ? hn : 0.f;
            if (msk) h0r = hn;
            ys[((long long)(b * S + s)) * H + k0g] = y;
            u16 hi = f2bf(h0r);
            unsigned packed = (unsigned)hi | ((unsigned)f2bf(h0r - bf2f(hi)) << 16);
            __hip_atomic_store(&hpub[b * EKP + k0g], packed, __ATOMIC_RELAXED,
                               __HIP_MEMORY_SCOPE_AGENT);
        }
        if (has1) {   // cell pair1: component c=4 (rows 4, 9, 14)
            float ghr = ghw[4 * 17 + b];
            float ghz = ghw[9 * 17 + b];
            float ghn = ghw[14 * 17 + b];
            float rg = sigm(gr1 + ghr + bhr1);
            float zg = sigm(gz1 + ghz + bhz1);
            float ng = tanhf(gn1 + rg * (ghn + bhn1));
            float hn = (1.f - zg) * ng + zg * h1r;
            bool msk = s < len;
            float y = msk ? hn : 0.f;
            if (msk) h1r = hn;
            ys[((long long)(b * S + s)) * H + k1g] = y;
            u16 hi = f2bf(h1r);
            unsigned packed = (unsigned)hi | ((unsigned)f2bf(h1r - bf2f(hi)) << 16);
            __hip_atomic_store(&hpub[b * EKP + k1g], packed, __ATOMIC_RELAXED,
                               __HIP_MEMORY_SCOPE_AGENT);
        }
        // per-wave drain: THIS wave's write-through publishes are at L3
        asm volatile("s_waitcnt vmcnt(0)" ::: "memory");
        if (lane == 0)
            __hip_atomic_store(&flg_d[t * NFLG + j * 4 + w], 1, __ATOMIC_RELAXED,
                               __HIP_MEMORY_SCOPE_AGENT);
    }
    ho[b * H + k0g] = h0r;
    if (has1) ho[b * H + k1g] = h1r;
}

// E = ys_f + ys_b (bf16, [b][s][k]) and ET (bf16, [b][k][s])
__global__ void packE_kernel(const float* __restrict__ ysf, const float* __restrict__ ysb,
                             u16* __restrict__ E, u16* __restrict__ ET) {
    __shared__ u16 tile[32][400];
    const int b = blockIdx.x, s0 = blockIdx.y * 32;
    for (int si = 0; si < 32; ++si) {
        const long long base = ((long long)b * S + s0 + si) * H;
        for (int k = threadIdx.x; k < H; k += blockDim.x) {
            u16 v = f2bf(ysf[base + k] + ysb[base + k]);
            E[base + k] = v;
            tile[si][k] = v;
        }
    }
    __syncthreads();
    for (int idx = threadIdx.x; idx < 32 * H; idx += blockDim.x) {
        int k = idx >> 5, si = idx & 31;
        ET[((long long)b * H + k) * S + s0 + si] = tile[si][k];
    }
}

__global__ void h0_kernel(const float* __restrict__ hf, const float* __restrict__ hb,
                          float* __restrict__ hf32, u16* __restrict__ hnk) {
    int n = blockIdx.x, b = n & 15;
    for (int k = threadIdx.x; k < H; k += blockDim.x) {
        float v = hf[b * H + k] + hb[b * H + k];
        hf32[(long long)n * H + k] = v;
        hnk[(long long)n * H + k] = f2bf(v);
    }
}

// ---------------------------------------------------------------------------
// Fused decoder step: block = batch b (16 blocks, 512 threads, dynamic LDS).
// ---------------------------------------------------------------------------
__global__ __launch_bounds__(512) void fused_step_kernel(
    const float* __restrict__ dgi, const float* __restrict__ dgh,
    float* __restrict__ hf32, u16* __restrict__ hall,
    const u16* __restrict__ decinb,
    const u16* __restrict__ Eb, const u16* __restrict__ ETb,
    const int* __restrict__ lens,
    const float* __restrict__ Wr, const float* __restrict__ br,
    const float* __restrict__ Wg, const float* __restrict__ bg,
    float* __restrict__ probfT, float* __restrict__ swvT,
    float* __restrict__ gout, int t)
{
    extern __shared__ char smem[];
    u16*   hls = (u16*)smem;                                   // [32][HP2]
    float* scs = (float*)(smem + 32 * HP2 * 2);                // [32][SCP]
    u16*   pls = (u16*)(smem + 32 * HP2 * 2 + 32 * SCP * 4);   // [32][PP]
    float* cxs = (float*)(smem + 32 * HP2 * 2 + 32 * SCP * 4 + 32 * PP * 2); // [32][CXP]

    const int b = blockIdx.x;
    const int tid = threadIdx.x, wave = tid >> 6, lane = tid & 63;
    const int fr = lane & 15, kq = lane >> 4;
    const int len = lens[b];

    for (int i = tid; i < 32 * (HP2 - H); i += 512) {
        int r = i / (HP2 - H), c = H + i % (HP2 - H);
        hls[r * HP2 + c] = 0;
    }
    for (int i = tid; i < 2 * HP2; i += 512) hls[30 * HP2 + i] = 0;
    for (int i = tid; i < 2 * PP; i += 512) pls[30 * PP + i] = 0;

    // P0: GRU cell for the 30 slots of this batch
    for (int i = tid; i < 30 * H; i += 512) {
        int slot = i / H, k = i % H;
        int n = slot * 16 + b;
        const float* gi = dgi + ((long long)t * NB + n) * H3;
        const float* gh = dgh + (long long)n * H3;
        float r  = sigm(gi[k] + gh[k]);
        float z  = sigm(gi[H + k] + gh[H + k]);
        float nn = tanhf(gi[2 * H + k] + r * gh[2 * H + k]);
        float h  = hf32[(long long)n * H + k];
        float hn = (1.f - z) * nn + z * h;
        hf32[(long long)n * H + k] = hn;
        u16 hb = f2bf(hn);
        hall[((long long)t * NB + n) * H + k] = hb;
        hls[slot * HP2 + k] = hb;
    }
    __syncthreads();

    // P1: scores[slot][s] = h . E[b][s]   (M=32, N=256, K=400)
    {
        const int nt0 = wave * 2;
        f32x4 acc[2][2];
#pragma unroll
        for (int i = 0; i < 2; ++i)
#pragma unroll
            for (int jj = 0; jj < 2; ++jj) acc[i][jj] = (f32x4){0.f, 0.f, 0.f, 0.f};
        const u16* br0 = Eb + ((long long)b * S + nt0 * 16 + fr) * H + kq * 8;
        const u16* br1 = Eb + ((long long)b * S + (nt0 + 1) * 16 + fr) * H + kq * 8;
        const u16* ar0 = hls + fr * HP2 + kq * 8;
        const u16* ar1 = hls + (16 + fr) * HP2 + kq * 8;
#pragma unroll
        for (int kk = 0; kk < 13; ++kk) {
            bf16x8 av0 = *(const bf16x8*)(ar0 + kk * 32);
            bf16x8 av1 = *(const bf16x8*)(ar1 + kk * 32);
            bf16x8 bv0, bv1;
            if (kk == 12 && kq >= 2) {
                bv0 = (bf16x8){0,0,0,0,0,0,0,0}; bv1 = bv0;
            } else {
                bv0 = *(const bf16x8*)(br0 + kk * 32);
                bv1 = *(const bf16x8*)(br1 + kk * 32);
            }
            acc[0][0] = __builtin_amdgcn_mfma_f32_16x16x32_bf16(av0, bv0, acc[0][0], 0, 0, 0);
            acc[1][0] = __builtin_amdgcn_mfma_f32_16x16x32_bf16(av1, bv0, acc[1][0], 0, 0, 0);
            acc[0][1] = __builtin_amdgcn_mfma_f32_16x16x32_bf16(av0, bv1, acc[0][1], 0, 0, 0);
            acc[1][1] = __builtin_amdgcn_mfma_f32_16x16x32_bf16(av1, bv1, acc[1][1], 0, 0, 0);
        }
#pragma unroll
        for (int i = 0; i < 2; ++i)
#pragma unroll
            for (int jj = 0; jj < 2; ++jj)
#pragma unroll
                for (int r = 0; r < 4; ++r)
                    scs[(i * 16 + kq * 4 + r) * SCP + (nt0 + jj) * 16 + fr] = acc[i][jj][r];
    }
    __syncthreads();

    // P2: softmax rows
    for (int i = 0; i < 4; ++i) {
        int row = wave * 4 + i;
        if (row >= 30) break;
        int n = row * 16 + b;
        float v[4];
        float mx = -3.0e38f;
#pragma unroll
        for (int q = 0; q < 4; ++q) {
            int s = lane + 64 * q;
            float x = (s < len) ? scs[row * SCP + s] : -3.0e38f;
            v[q] = x; mx = fmaxf(mx, x);
        }
        mx = fmaxf(mx, __shfl_xor(mx, 1));  mx = fmaxf(mx, __shfl_xor(mx, 2));
        mx = fmaxf(mx, __shfl_xor(mx, 4));  mx = fmaxf(mx, __shfl_xor(mx, 8));
        mx = fmaxf(mx, __shfl_xor(mx, 16)); mx = fmaxf(mx, __shfl_xor(mx, 32));
        float sum = 0.f;
#pragma unroll
        for (int q = 0; q < 4; ++q) {
            int s = lane + 64 * q;
            float e = (s < len) ? __expf(v[q] - mx) : 0.f;
            v[q] = e; sum += e;
        }
        sum += __shfl_xor(sum, 1);  sum += __shfl_xor(sum, 2);
        sum += __shfl_xor(sum, 4);  sum += __shfl_xor(sum, 8);
        sum += __shfl_xor(sum, 16); sum += __shfl_xor(sum, 32);
        float inv = 1.f / sum;
#pragma unroll
        for (int q = 0; q < 4; ++q) {
            int s = lane + 64 * q;
            float pr = v[q] * inv;
            pls[row * PP + s] = f2bf(pr);
            probfT[((long long)(t * NB + n)) * S + s] = pr;
        }
    }
    __syncthreads();

    // P3: ctx[slot][k] = sum_s prob[slot][s] * ET[b][k][s]
    for (int nt = wave; nt < 25; nt += 8) {
        f32x4 acc0 = (f32x4){0.f,0.f,0.f,0.f}, acc1 = (f32x4){0.f,0.f,0.f,0.f};
        const u16* brow = ETb + ((long long)b * H + nt * 16 + fr) * S + kq * 8;
        const u16* ar0 = pls + fr * PP + kq * 8;
        const u16* ar1 = pls + (16 + fr) * PP + kq * 8;
#pragma unroll
        for (int kk = 0; kk < 8; ++kk) {
            bf16x8 bv  = *(const bf16x8*)(brow + kk * 32);
            bf16x8 av0 = *(const bf16x8*)(ar0 + kk * 32);
            bf16x8 av1 = *(const bf16x8*)(ar1 + kk * 32);
            acc0 = __builtin_amdgcn_mfma_f32_16x16x32_bf16(av0, bv, acc0, 0, 0, 0);
            acc1 = __builtin_amdgcn_mfma_f32_16x16x32_bf16(av1, bv, acc1, 0, 0, 0);
        }
#pragma unroll
        for (int r = 0; r < 4; ++r) {
            cxs[(kq * 4 + r) * CXP + nt * 16 + fr] = acc0[r];
            cxs[(16 + kq * 4 + r) * CXP + nt * 16 + fr] = acc1[r];
        }
    }
    __syncthreads();

    // P4: p_gen switch (+ gate at t==0)
    for (int i = 0; i < 4; ++i) {
        int slot = wave + 8 * i;
        if (slot >= 30) break;
        int n = slot * 16 + b;
        const u16* xrow = decinb + ((long long)t * NB + n) * H;
        float p = 0.f;
        for (int k = lane; k < H; k += 64)
            p += bf2f(hls[slot * HP2 + k]) * Wr[k]
               + cxs[slot * CXP + k] * Wr[H + k]
               + bf2f(xrow[k]) * Wr[2 * H + k];
        p += __shfl_xor(p, 1);  p += __shfl_xor(p, 2);
        p += __shfl_xor(p, 4);  p += __shfl_xor(p, 8);
        p += __shfl_xor(p, 16); p += __shfl_xor(p, 32);
        if (lane == 0) swvT[t * NB + n] = sigm(p + br[0]);
        if (t == 0) {
            for (int g = 0; g < G; ++g) {
                float q = 0.f;
                for (int k = lane; k < H; k += 64)
                    q += cxs[slot * CXP + k] * Wg[g * H + k];
                q += __shfl_xor(q, 1);  q += __shfl_xor(q, 2);
                q += __shfl_xor(q, 4);  q += __shfl_xor(q, 8);
                q += __shfl_xor(q, 16); q += __shfl_xor(q, 32);
                if (lane == 0) gout[(long long)n * G + g] = q + bg[g];
            }
        }
    }
}

// scale all t at once: out[n][t][:] *= sw[t][n] / rowsum[t*NB+n]
__global__ void scale_all_kernel(float* __restrict__ out, const float* __restrict__ swvT,
                                 const float* __restrict__ rowsumT) {
    const int n = blockIdx.x;
    const int col = blockIdx.y * 256 + threadIdx.x;
    if (col >= V) return;
#pragma unroll
    for (int t = 0; t < T; ++t) {
        float f = swvT[t * NB + n] / rowsumT[t * NB + n];
        out[((long long)n * T + t) * V + col] *= f;
    }
}

__global__ void scatter_all_kernel(float* __restrict__ out, const int* __restrict__ story,
                                   const int* __restrict__ lens, const float* __restrict__ swvT,
                                   const float* __restrict__ probfT) {
    const int n = blockIdx.x, t = blockIdx.y, b = n & 15, s = threadIdx.x;
    if (s < lens[b]) {
        int tok = story[b * S + s];
        atomicAdd(out + ((long long)n * T + t) * V + tok,
                  (1.f - swvT[t * NB + n]) * probfT[((long long)(t * NB + n)) * S + s]);
    }
}

// ---------------------------------------------------------------------------
extern "C" void kernel_launch(void* const* d_in, const int* in_sizes, int n_in,
                              void* d_out, int out_size, void* d_ws, size_t ws_size,
                              hipStream_t stream) {
    const int*   story = (const int*)d_in[0];
    const int*   lens  = (const int*)d_in[1];
    const int*   tgt   = (const int*)d_in[2];
    const int*   dom   = (const int*)d_in[3];
    const int*   sidx  = (const int*)d_in[4];
    const float* emb   = (const float*)d_in[5];
    const float* wihf  = (const float*)d_in[6];
    const float* whhf  = (const float*)d_in[7];
    const float* bihf  = (const float*)d_in[8];
    const float* bhhf  = (const float*)d_in[9];
    const float* wihb  = (const float*)d_in[10];
    const float* whhb  = (const float*)d_in[11];
    const float* bihb  = (const float*)d_in[12];
    const float* bhhb  = (const float*)d_in[13];
    const float* dwih  = (const float*)d_in[14];
    const float* dwhh  = (const float*)d_in[15];
    const float* dbih  = (const float*)d_in[16];
    const float* dbhh  = (const float*)d_in[17];
    const float* Wr    = (const float*)d_in[18];
    const float* br    = (const float*)d_in[19];
    const float* Wg    = (const float*)d_in[20];
    const float* bg    = (const float*)d_in[21];
    const float* slt   = (const float*)d_in[22];
    float* out = (float*)d_out;

    char* wsb = (char*)d_ws;
    size_t off = 0;
    auto alloc = [&](size_t bytes) -> char* {
        char* p = wsb + off;
        off += (bytes + 255) & ~(size_t)255;
        return p;
    };
    u16*   embb   = (u16*)alloc((size_t)V * H * 2);
    u16*   wihfb  = (u16*)alloc((size_t)H3 * H * 2);
    u16*   wihbb  = (u16*)alloc((size_t)H3 * H * 2);
    u16*   dwihb  = (u16*)alloc((size_t)H3 * H * 2);
    u16*   dwhhb  = (u16*)alloc((size_t)H3 * H * 2);
    u16*   wencp  = (u16*)alloc((size_t)2 * ENBLK * EROWS * EKP * 2);
    unsigned* hbuf = (unsigned*)alloc((size_t)2 * S * B * EKP * 4);   // 13.6 MB rotating
    int*   flags  = (int*)alloc((size_t)2 * S * NFLG * 4);            // 160 KB rotating
    u16*   xb     = (u16*)alloc((size_t)S * B * H * 2);
    u16*   decinb = (u16*)alloc((size_t)T * NB * H * 2);
    float* gif    = (float*)alloc((size_t)S * B * H3 * 4);
    float* gib    = (float*)alloc((size_t)S * B * H3 * 4);
    float* dgi    = (float*)alloc((size_t)T * NB * H3 * 4);
    float* ysf    = (float*)alloc((size_t)B * S * H * 4);
    float* ysb    = (float*)alloc((size_t)B * S * H * 4);
    float* hfv    = (float*)alloc((size_t)B * H * 4);
    float* hbv    = (float*)alloc((size_t)B * H * 4);
    u16*   Eb     = (u16*)alloc((size_t)B * S * H * 2);
    u16*   ETb    = (u16*)alloc((size_t)B * H * S * 2);
    float* hf32   = (float*)alloc((size_t)NB * H * 4);
    u16*   hnk    = (u16*)alloc((size_t)NB * H * 2);
    u16*   hall   = (u16*)alloc((size_t)T * NB * H * 2);
    float* dgh    = (float*)alloc((size_t)NB * H3 * 4);
    float* probfT = (float*)alloc((size_t)T * NB * S * 4);
    float* swvT   = (float*)alloc((size_t)T * NB * 4);
    float* rowsumT = (float*)alloc((size_t)T * NB * 4);
    (void)ws_size; (void)in_sizes; (void)n_in; (void)out_size;

    auto launch_gemm = [&](const u16* A, const u16* Bt, const float* bias, float* C,
                           int M, int N, int K, int lda, int ldb, long long ldc,
                           long long sA, long long sB, long long sC, int nb,
                           int mode, float* rs) {
        dim3 g((M + 63) / 64, (N + 63) / 64, nb);
        gemm_bt<<<g, 256, 0, stream>>>(A, Bt, bias, C, M, N, K, lda, ldb, ldc,
                                       sA, sB, sC, mode, rs);
    };

    hipFuncSetAttribute((const void*)fused_step_kernel,
                        hipFuncAttributeMaxDynamicSharedMemorySize, FUSED_LDS);

    // ---- setup: casts, embeddings, input-side GEMMs -----------------------
    cvt_bf16_kernel<<<2048, 256, 0, stream>>>(emb, embb, V * H);
    cvt4_kernel<<<1024, 256, 0, stream>>>(wihf, wihb, dwih, dwhh,
                                          wihfb, wihbb, dwihb, dwhhb, H3 * H);
    {
        const int total = 2 * ENBLK * EROWS * EKP;
        prep_wenc_kernel<<<(total + 255) / 256, 256, 0, stream>>>(whhf, whhb, wencp);
    }
    embed_story_kernel<<<S * B, 256, 0, stream>>>(story, embb, xb);
    { dim3 g(NB, T); build_decin_kernel<<<g, 256, 0, stream>>>(tgt, dom, sidx, slt, embb, decinb); }

    launch_gemm(xb, wihfb, bihf, gif, S * B, H3, H, H, H, H3, 0, 0, 0, 1, 0, nullptr);
    launch_gemm(xb, wihbb, bihb, gib, S * B, H3, H, H, H, H3, 0, 0, 0, 1, 0, nullptr);
    launch_gemm(decinb, dwihb, dbih, dgi, T * NB, H3, H, H, H, H3, 0, 0, 0, 1, 0, nullptr);

    // ---- encoder recurrence (protocol v7: barrier-free wave-sync) ---------
    hipMemsetAsync(flags, 0, (size_t)2 * S * NFLG * 4, stream);
    hipMemsetAsync(hbuf, 0, (size_t)2 * S * B * EKP * 4, stream);
    hipMemsetAsync(rowsumT, 0, (size_t)T * NB * 4, stream);
    enc_rnn_bf_kernel<<<2 * ENBLK, 256, 0, stream>>>(wencp, bhhf, bhhb, gif, gib, lens,
                                                     hbuf, flags, ysf, ysb, hfv, hbv);
    { dim3 g(B, S / 32); packE_kernel<<<g, 256, 0, stream>>>(ysf, ysb, Eb, ETb); }
    h0_kernel<<<NB, 256, 0, stream>>>(hfv, hbv, hf32, hnk);

    // ---- decoder: sequential chain (2 launches/step) ----------------------
    for (int t = 0; t < T; ++t) {
        const u16* hprev = (t == 0) ? hnk : hall + (size_t)(t - 1) * NB * H;
        launch_gemm(hprev, dwhhb, dbhh, dgh, NB, H3, H, H, H, H3, 0, 0, 0, 1, 0, nullptr);
        fused_step_kernel<<<16, 512, FUSED_LDS, stream>>>(
            dgi, dgh, hf32, hall, decinb, Eb, ETb, lens, Wr, br, Wg, bg,
            probfT, swvT, out + (size_t)NB * T * V, t);
    }

    // ---- batched vocab projection: one GEMM over all (t, n) rows ----------
    launch_gemm(hall, embb, nullptr, out, T * NB, V, H, H, H, V,
                0, 0, 0, 1, 2, rowsumT);
    { dim3 g(NB, (V + 255) / 256); scale_all_kernel<<<g, 256, 0, stream>>>(out, swvT, rowsumT); }
    { dim3 g(NB, T); scatter_all_kernel<<<g, 256, 0, stream>>>(out, story, lens, swvT, probfT); }
}

// Round 10
// 2952.954 us; speedup vs baseline: 1.0619x; 1.0619x over previous
//
#include <hip/hip_runtime.h>
#include <hip/hip_bf16.h>

typedef unsigned short u16;
typedef __attribute__((ext_vector_type(8))) short bf16x8;
typedef __attribute__((ext_vector_type(4))) float f32x4;
typedef __attribute__((ext_vector_type(4))) unsigned u32x4;

static constexpr int V = 20000, H = 400, B = 16, S = 256, NSLOT = 30, T = 10, G = 3;
static constexpr int H3 = 3 * H;           // 1200
static constexpr int NB = NSLOT * B;       // 480
// encoder partition (R8 protocol — best measured)
static constexpr int ENBLK = 20;           // blocks per direction
static constexpr int ESL   = 20;           // h components per block (400/20)
static constexpr int EROWS = 64;           // padded weight rows per block
static constexpr int EKP   = 416;          // padded K
// fused decoder LDS strides
static constexpr int HP2 = 424;            // h_lds row stride (u16)
static constexpr int SCP = 260;            // scores row stride (f32)
static constexpr int PP  = 264;            // prob row stride (u16)
static constexpr int CXP = 404;            // ctx row stride (f32)
static constexpr int FUSED_LDS = 32*HP2*2 + 32*SCP*4 + 32*PP*2 + 32*CXP*4; // 129024

__device__ __forceinline__ float bf2f(u16 v) {
    union { unsigned u; float f; } x; x.u = ((unsigned)v) << 16; return x.f;
}
__device__ __forceinline__ u16 f2bf(float f) {
    union { float f; unsigned u; } x; x.f = f;
    unsigned r = x.u + 0x7fffu + ((x.u >> 16) & 1u);   // round-to-nearest-even
    return (u16)(r >> 16);
}
__device__ __forceinline__ float sigm(float v) { return 1.f / (1.f + __expf(-v)); }

// ---------------------------------------------------------------------------
// Generic batched GEMM: C[m][n] = sum_k A[m][k] * Bt[n][k]  (+bias[n])
// mode 0: plain (+bias). mode 1: C=exp(acc)+rowsum, ldc layout.
// mode 2: C=exp(acc)+rowsum, vocab layout: row=t*NB+n -> C[((n*T)+t)*V + col].
// ---------------------------------------------------------------------------
__global__ __launch_bounds__(256) void gemm_bt(
    const u16* __restrict__ A, const u16* __restrict__ Bt,
    const float* __restrict__ bias, float* __restrict__ C,
    int M, int N, int K, int lda, int ldb, long long ldc,
    long long sA, long long sB, long long sC,
    int mode, float* __restrict__ rowsum)
{
    __shared__ u16 As[64][40];
    __shared__ u16 Bs[64][40];
    const int bz = blockIdx.z;
    A  += (long long)bz * sA;
    Bt += (long long)bz * sB;
    C  += (long long)bz * sC;
    const int m0 = blockIdx.x * 64, n0 = blockIdx.y * 64;
    const int tid = threadIdx.x, wave = tid >> 6, lane = tid & 63;
    const int wm = (wave >> 1) * 32, wn = (wave & 1) * 32;
    const int srow = tid >> 2, scol = (tid & 3) * 8;
    const int fr = lane & 15, kq = lane >> 4;
    f32x4 acc[2][2];
#pragma unroll
    for (int i = 0; i < 2; ++i)
#pragma unroll
        for (int j = 0; j < 2; ++j) acc[i][j] = (f32x4){0.f, 0.f, 0.f, 0.f};

    for (int k0 = 0; k0 < K; k0 += 32) {
        {
            int gr = m0 + srow, gc = k0 + scol;
            bf16x8 v;
            if (gr < M && gc + 8 <= K) {
                v = *(const bf16x8*)(A + (long long)gr * lda + gc);
            } else {
                short tmp[8];
#pragma unroll
                for (int j = 0; j < 8; ++j)
                    tmp[j] = (gr < M && gc + j < K) ? (short)A[(long long)gr * lda + gc + j] : (short)0;
                v = *(bf16x8*)tmp;
            }
            *(bf16x8*)&As[srow][scol] = v;
        }
        {
            int gr = n0 + srow, gc = k0 + scol;
            bf16x8 v;
            if (gr < N && gc + 8 <= K) {
                v = *(const bf16x8*)(Bt + (long long)gr * ldb + gc);
            } else {
                short tmp[8];
#pragma unroll
                for (int j = 0; j < 8; ++j)
                    tmp[j] = (gr < N && gc + j < K) ? (short)Bt[(long long)gr * ldb + gc + j] : (short)0;
                v = *(bf16x8*)tmp;
            }
            *(bf16x8*)&Bs[srow][scol] = v;
        }
        __syncthreads();
        bf16x8 af[2], bfr[2];
#pragma unroll
        for (int i = 0; i < 2; ++i) af[i]  = *(const bf16x8*)&As[wm + i * 16 + fr][kq * 8];
#pragma unroll
        for (int j = 0; j < 2; ++j) bfr[j] = *(const bf16x8*)&Bs[wn + j * 16 + fr][kq * 8];
#pragma unroll
        for (int i = 0; i < 2; ++i)
#pragma unroll
            for (int j = 0; j < 2; ++j)
                acc[i][j] = __builtin_amdgcn_mfma_f32_16x16x32_bf16(af[i], bfr[j], acc[i][j], 0, 0, 0);
        __syncthreads();
    }

#pragma unroll
    for (int i = 0; i < 2; ++i)
#pragma unroll
        for (int j = 0; j < 2; ++j) {
            int col = n0 + wn + j * 16 + fr;
            float bv = (bias != nullptr && col < N) ? bias[col] : 0.f;
#pragma unroll
            for (int r = 0; r < 4; ++r) {
                int row = m0 + wm + i * 16 + kq * 4 + r;
                bool ok = (row < M) && (col < N);
                float v = acc[i][j][r] + bv;
                if (mode >= 1) { v = ok ? __expf(v) : 0.f; acc[i][j][r] = v; }
                if (ok) {
                    long long coff;
                    if (mode == 2)
                        coff = ((long long)(row % NB) * T + (row / NB)) * (long long)V + col;
                    else
                        coff = (long long)row * ldc + col;
                    C[coff] = v;
                }
            }
        }
    if (mode >= 1) {
#pragma unroll
        for (int i = 0; i < 2; ++i)
#pragma unroll
            for (int r = 0; r < 4; ++r) {
                float s = acc[i][0][r] + acc[i][1][r];
                s += __shfl_xor(s, 1); s += __shfl_xor(s, 2);
                s += __shfl_xor(s, 4); s += __shfl_xor(s, 8);
                if (fr == 0) {
                    int row = m0 + wm + i * 16 + kq * 4 + r;
                    if (row < M) atomicAdd(&rowsum[row], s);
                }
            }
    }
}

// ---------------------------------------------------------------------------
// small utility kernels
// ---------------------------------------------------------------------------
__global__ void cvt_bf16_kernel(const float* __restrict__ src, u16* __restrict__ dst, int n) {
    for (int i = blockIdx.x * blockDim.x + threadIdx.x; i < n; i += gridDim.x * blockDim.x)
        dst[i] = f2bf(src[i]);
}

__global__ void cvt4_kernel(const float* __restrict__ a, const float* __restrict__ b,
                            const float* __restrict__ c, const float* __restrict__ d,
                            u16* __restrict__ da, u16* __restrict__ db,
                            u16* __restrict__ dc, u16* __restrict__ dd, int n) {
    for (int i = blockIdx.x * blockDim.x + threadIdx.x; i < n; i += gridDim.x * blockDim.x) {
        da[i] = f2bf(a[i]); db[i] = f2bf(b[i]); dc[i] = f2bf(c[i]); dd[i] = f2bf(d[i]);
    }
}

// weight prep for the distributed encoder: dst[dir][j][rloc][k], rloc = g*20+c
__global__ void prep_wenc_kernel(const float* __restrict__ whhf, const float* __restrict__ whhb,
                                 u16* __restrict__ dst) {
    int idx = blockIdx.x * 256 + threadIdx.x;
    const int total = 2 * ENBLK * EROWS * EKP;
    if (idx >= total) return;
    int k = idx % EKP; int r = idx / EKP;
    int rloc = r % EROWS; r /= EROWS;
    int j = r % ENBLK; int dir = r / ENBLK;
    u16 v = 0;
    if (k < H && rloc < 3 * ESL) {
        int g = rloc / ESL, c = rloc % ESL;
        const float* W = dir ? whhb : whhf;
        v = f2bf(W[(long long)(g * H + j * ESL + c) * H + k]);
    }
    dst[idx] = v;
}

__global__ void embed_story_kernel(const int* __restrict__ story, const u16* __restrict__ embb,
                                   u16* __restrict__ xb) {
    int row = blockIdx.x;                 // row = s*16 + b
    int s = row >> 4, b = row & 15;
    int tok = story[b * S + s];
    const u16* e = embb + (long long)tok * H;
    u16* d = xb + (long long)row * H;
    for (int k = threadIdx.x; k < H; k += blockDim.x) d[k] = e[k];
}

__global__ void build_decin_kernel(const int* __restrict__ tgt, const int* __restrict__ dom,
                                   const int* __restrict__ sidx, const float* __restrict__ slt,
                                   const u16* __restrict__ embb, u16* __restrict__ decin) {
    int n = blockIdx.x, t = blockIdx.y;
    int b = n & 15, slot = n >> 4;
    u16* d = decin + ((long long)t * NB + n) * H;
    if (t == 0) {
        const float* s1 = slt + (long long)dom[slot] * H;
        const float* s2 = slt + (long long)sidx[slot] * H;
        for (int k = threadIdx.x; k < H; k += blockDim.x) d[k] = f2bf(s1[k] + s2[k]);
    } else {
        int tok = tgt[(b * NSLOT + slot) * T + (t - 1)];
        const u16* e = embb + (long long)tok * H;
        for (int k = threadIdx.x; k < H; k += blockDim.x) d[k] = e[k];
    }
}

// ---------------------------------------------------------------------------
// Distributed encoder recurrence — R8 protocol v6 VERBATIM (best measured):
// rotating hbuf/flags, relaxed agent write-through publish, block barrier
// (vmcnt0 drain), tid0 relaxed flag store; readers poll relaxed + plain
// dwordx4 loads at never-before-read addresses (L2-cold -> L3-fresh).
// ---------------------------------------------------------------------------
__global__ __launch_bounds__(256) void enc_rnn2_kernel(
    const u16* __restrict__ wencp,
    const float* __restrict__ bhhf, const float* __restrict__ bhhb,
    const float* __restrict__ gif, const float* __restrict__ gib,
    const int* __restrict__ lens,
    unsigned* __restrict__ hbuf, int* __restrict__ flags,
    float* __restrict__ ysf, float* __restrict__ ysb,
    float* __restrict__ hfo, float* __restrict__ hbo)
{
    const int bid = blockIdx.x;
    const int dir = bid / ENBLK, j = bid % ENBLK;
    const float* bhh = dir ? bhhb : bhhf;
    const float* gi  = dir ? gib  : gif;
    float* ys = dir ? ysb : ysf;
    float* ho = dir ? hbo : hfo;

    __shared__ u16 wlds[EROWS * EKP];      // 53248 B
    __shared__ float ghs[EROWS * 17];      // 4352 B

    const int tid = threadIdx.x, wave = tid >> 6, lane = tid & 63;
    const int fr = lane & 15, kq = lane >> 4;

    const u16* wsrc = wencp + (long long)(dir * ENBLK + j) * EROWS * EKP;
    for (int i = tid * 8; i < EROWS * EKP; i += 256 * 8)
        *(bf16x8*)&wlds[i] = *(const bf16x8*)&wsrc[i];
    for (int i = tid; i < EROWS * 17; i += 256) ghs[i] = 0.f;

    const int p0 = tid, p1 = 256 + tid;
    const bool has1 = (tid < 64);
    const int b0 = p0 / ESL, kl0 = p0 % ESL;
    const int b1 = has1 ? p1 / ESL : 0, kl1 = has1 ? p1 % ESL : 0;
    const int k0 = j * ESL;
    const int len0 = lens[b0];
    const int len1 = has1 ? lens[b1] : 0;
    const float bhr0 = bhh[k0 + kl0], bhz0 = bhh[H + k0 + kl0], bhn0 = bhh[2 * H + k0 + kl0];
    const float bhr1 = has1 ? bhh[k0 + kl1] : 0.f;
    const float bhz1 = has1 ? bhh[H + k0 + kl1] : 0.f;
    const float bhn1 = has1 ? bhh[2 * H + k0 + kl1] : 0.f;
    float h0r = 0.f, h1r = 0.f;

    unsigned* hb_d = hbuf + (long long)dir * S * B * EKP;
    int* flg_d = flags + dir * S * ENBLK;
    const u16* arow = &wlds[(wave * 16 + fr) * EKP + kq * 8];
    __syncthreads();

    for (int t = 0; t < S; ++t) {
        const int s = dir ? (S - 1 - t) : t;
        const float* gbase = gi + (long long)s * B * H3;
        float gr0 = gbase[b0 * H3 + k0 + kl0];
        float gz0 = gbase[b0 * H3 + H + k0 + kl0];
        float gn0 = gbase[b0 * H3 + 2 * H + k0 + kl0];
        float gr1 = 0.f, gz1 = 0.f, gn1 = 0.f;
        if (has1) {
            gr1 = gbase[b1 * H3 + k0 + kl1];
            gz1 = gbase[b1 * H3 + H + k0 + kl1];
            gn1 = gbase[b1 * H3 + 2 * H + k0 + kl1];
        }

        f32x4 acc = (f32x4){0.f, 0.f, 0.f, 0.f};
        if (t > 0) {
            const int* fl = flg_d + (t - 1) * ENBLK;
            for (;;) {
                int v = 1;
                if (lane < ENBLK)
                    v = __hip_atomic_load(&fl[lane], __ATOMIC_RELAXED,
                                          __HIP_MEMORY_SCOPE_AGENT);
                if (__all(v != 0)) break;
                __builtin_amdgcn_s_sleep(2);
            }
            asm volatile("" ::: "memory");   // keep hbuf reads after the poll
            const unsigned* hrow = hb_d + ((long long)(t - 1) * B + fr) * EKP + kq * 8;
            f32x4 acch = (f32x4){0.f, 0.f, 0.f, 0.f};
            f32x4 accl = (f32x4){0.f, 0.f, 0.f, 0.f};
#pragma unroll
            for (int kk = 0; kk < 13; ++kk) {
                u32x4 a = *(const u32x4*)(hrow + kk * 32);
                u32x4 b = *(const u32x4*)(hrow + kk * 32 + 4);
                union { unsigned u[4]; bf16x8 v; } hi, lo;
                hi.u[0] = __builtin_amdgcn_perm(a[1], a[0], 0x05040100u);
                hi.u[1] = __builtin_amdgcn_perm(a[3], a[2], 0x05040100u);
                hi.u[2] = __builtin_amdgcn_perm(b[1], b[0], 0x05040100u);
                hi.u[3] = __builtin_amdgcn_perm(b[3], b[2], 0x05040100u);
                lo.u[0] = __builtin_amdgcn_perm(a[1], a[0], 0x07060302u);
                lo.u[1] = __builtin_amdgcn_perm(a[3], a[2], 0x07060302u);
                lo.u[2] = __builtin_amdgcn_perm(b[1], b[0], 0x07060302u);
                lo.u[3] = __builtin_amdgcn_perm(b[3], b[2], 0x07060302u);
                bf16x8 av = *(const bf16x8*)(arow + kk * 32);
                acch = __builtin_amdgcn_mfma_f32_16x16x32_bf16(av, hi.v, acch, 0, 0, 0);
                accl = __builtin_amdgcn_mfma_f32_16x16x32_bf16(av, lo.v, accl, 0, 0, 0);
            }
            acc = acch + accl;
        }
#pragma unroll
        for (int r = 0; r < 4; ++r) ghs[(wave * 16 + kq * 4 + r) * 17 + fr] = acc[r];
        __syncthreads();

        unsigned* hpub = hb_d + (long long)t * B * EKP;
        {
            float ghr = ghs[kl0 * 17 + b0];
            float ghz = ghs[(ESL + kl0) * 17 + b0];
            float ghn = ghs[(2 * ESL + kl0) * 17 + b0];
            float rg = sigm(gr0 + ghr + bhr0);
            float zg = sigm(gz0 + ghz + bhz0);
            float ng = tanhf(gn0 + rg * (ghn + bhn0));
            float hn = (1.f - zg) * ng + zg * h0r;
            bool msk = s < len0;
            float y = msk ? hn : 0.f;
            if (msk) h0r = hn;
            ys[((long long)(b0 * S + s)) * H + k0 + kl0] = y;
            u16 hi = f2bf(h0r);
            unsigned packed = (unsigned)hi | ((unsigned)f2bf(h0r - bf2f(hi)) << 16);
            __hip_atomic_store(&hpub[b0 * EKP + k0 + kl0], packed, __ATOMIC_RELAXED,
                               __HIP_MEMORY_SCOPE_AGENT);
        }
        if (has1) {
            float ghr = ghs[kl1 * 17 + b1];
            float ghz = ghs[(ESL + kl1) * 17 + b1];
            float ghn = ghs[(2 * ESL + kl1) * 17 + b1];
            float rg = sigm(gr1 + ghr + bhr1);
            float zg = sigm(gz1 + ghz + bhz1);
            float ng = tanhf(gn1 + rg * (ghn + bhn1));
            float hn = (1.f - zg) * ng + zg * h1r;
            bool msk = s < len1;
            float y = msk ? hn : 0.f;
            if (msk) h1r = hn;
            ys[((long long)(b1 * S + s)) * H + k0 + kl1] = y;
            u16 hi = f2bf(h1r);
            unsigned packed = (unsigned)hi | ((unsigned)f2bf(h1r - bf2f(hi)) << 16);
            __hip_atomic_store(&hpub[b1 * EKP + k0 + kl1], packed, __ATOMIC_RELAXED,
                               __HIP_MEMORY_SCOPE_AGENT);
        }
        __syncthreads();
        if (tid == 0)
            __hip_atomic_store(&flg_d[t * ENBLK + j], 1, __ATOMIC_RELAXED,
                               __HIP_MEMORY_SCOPE_AGENT);
    }
    ho[b0 * H + k0 + kl0] = h0r;
    if (has1) ho[b1 * H + k0 + kl1] = h1r;
}

// E = ys_f + ys_b (bf16, [b][s][k]) and ET (bf16, [b][k][s])
__global__ void packE_kernel(const float* __restrict__ ysf, const float* __restrict__ ysb,
                             u16* __restrict__ E, u16* __restrict__ ET) {
    __shared__ u16 tile[32][400];
    const int b = blockIdx.x, s0 = blockIdx.y * 32;
    for (int si = 0; si < 32; ++si) {
        const long long base = ((long long)b * S + s0 + si) * H;
        for (int k = threadIdx.x; k < H; k += blockDim.x) {
            u16 v = f2bf(ysf[base + k] + ysb[base + k]);
            E[base + k] = v;
            tile[si][k] = v;
        }
    }
    __syncthreads();
    for (int idx = threadIdx.x; idx < 32 * H; idx += blockDim.x) {
        int k = idx >> 5, si = idx & 31;
        ET[((long long)b * H + k) * S + s0 + si] = tile[si][k];
    }
}

// ---------------------------------------------------------------------------
// Persistent fused decoder: ONE launch, block = batch b, 512 threads.
// Per t: [dgh MFMA from LDS h + global dwhhb] -> [GRU cell in registers,
// new h staged in scs scratch] -> [copy to hls/hall] -> P1 scores -> P2
// softmax -> P3 ctx -> P4 p_gen (+gate t0). No inter-block deps.
// ---------------------------------------------------------------------------
__global__ __launch_bounds__(512) void decoder_persist_kernel(
    const float* __restrict__ dgi, const u16* __restrict__ dwhhb,
    const float* __restrict__ dbhh,
    const float* __restrict__ hfv, const float* __restrict__ hbv,
    u16* __restrict__ hall, const u16* __restrict__ decinb,
    const u16* __restrict__ Eb, const u16* __restrict__ ETb,
    const int* __restrict__ lens,
    const float* __restrict__ Wr, const float* __restrict__ br,
    const float* __restrict__ Wg, const float* __restrict__ bg,
    float* __restrict__ probfT, float* __restrict__ swvT,
    float* __restrict__ gout)
{
    extern __shared__ char smem[];
    u16*   hls = (u16*)smem;                                   // [32][HP2]
    float* scs = (float*)(smem + 32 * HP2 * 2);                // [32][SCP] (also scratch scs_h)
    u16*   pls = (u16*)(smem + 32 * HP2 * 2 + 32 * SCP * 4);   // [32][PP]
    float* cxs = (float*)(smem + 32 * HP2 * 2 + 32 * SCP * 4 + 32 * PP * 2); // [32][CXP]
    u16* scs_h = (u16*)scs;                                    // 30*400 u16 = 24 KB <= 33 KB

    const int b = blockIdx.x;
    const int tid = threadIdx.x, w = tid >> 6, lane = tid & 63;
    const int fr = lane & 15, kq = lane >> 4;
    const int len = lens[b];

    // zero pads (rows 30/31 fully; cols 400.. for all rows) — written once
    for (int i = tid; i < 32 * (HP2 - H); i += 512) {
        int r = i / (HP2 - H), c = H + i % (HP2 - H);
        hls[r * HP2 + c] = 0;
    }
    for (int i = tid; i < 2 * HP2; i += 512) hls[30 * HP2 + i] = 0;
    for (int i = tid; i < 2 * PP; i += 512) pls[30 * PP + i] = 0;

    // init h0 = enc_hidden (same for all slots): hls rows 0..29, hreg
    for (int i = tid; i < 30 * H; i += 512) {
        int slot = i / H, k = i % H;
        hls[slot * HP2 + k] = f2bf(hfv[b * H + k] + hbv[b * H + k]);
    }
    float hreg[4][2][4];
    float bhr[4], bhz[4], bhn[4];
#pragma unroll
    for (int q = 0; q < 4; ++q) {
        int kc = w + 8 * q;
        if (kc < 25) {
            int c = kc * 16 + fr;
            float h0 = hfv[b * H + c] + hbv[b * H + c];
            bhr[q] = dbhh[c]; bhz[q] = dbhh[H + c]; bhn[q] = dbhh[2 * H + c];
#pragma unroll
            for (int i = 0; i < 2; ++i)
#pragma unroll
                for (int r = 0; r < 4; ++r) hreg[q][i][r] = h0;
        }
    }
    __syncthreads();

    for (int t = 0; t < T; ++t) {
        // ---- dgh phase: gh = h_prev @ dwhh^T, per wave's column groups ----
#pragma unroll
        for (int q = 0; q < 4; ++q) {
            int kc = w + 8 * q;
            if (kc >= 25) continue;
            const int cb = kc * 16;
            const int c = cb + fr;
            f32x4 gacc[3][2];
#pragma unroll
            for (int g = 0; g < 3; ++g)
#pragma unroll
                for (int i = 0; i < 2; ++i) gacc[g][i] = (f32x4){0.f, 0.f, 0.f, 0.f};
#pragma unroll
            for (int g = 0; g < 3; ++g) {
                const u16* brow = dwhhb + (long long)(g * H + cb + fr) * H + kq * 8;
                const u16* ar0 = hls + fr * HP2 + kq * 8;
                const u16* ar1 = hls + (16 + fr) * HP2 + kq * 8;
#pragma unroll
                for (int kk = 0; kk < 13; ++kk) {
                    bf16x8 bv;
                    if (kk == 12 && kq >= 2) bv = (bf16x8){0,0,0,0,0,0,0,0};
                    else bv = *(const bf16x8*)(brow + kk * 32);
                    bf16x8 av0 = *(const bf16x8*)(ar0 + kk * 32);
                    bf16x8 av1 = *(const bf16x8*)(ar1 + kk * 32);
                    gacc[g][0] = __builtin_amdgcn_mfma_f32_16x16x32_bf16(av0, bv, gacc[g][0], 0, 0, 0);
                    gacc[g][1] = __builtin_amdgcn_mfma_f32_16x16x32_bf16(av1, bv, gacc[g][1], 0, 0, 0);
                }
            }
            // cell for this column group (writes go to scs_h scratch, not hls)
            const float* gbase = dgi + ((long long)t * NB + b) * H3;   // + slot*16*H3
#pragma unroll
            for (int i = 0; i < 2; ++i)
#pragma unroll
                for (int r = 0; r < 4; ++r) {
                    int slotr = i * 16 + kq * 4 + r;
                    if (slotr >= 30) continue;
                    const float* gir = gbase + (long long)slotr * 16 * H3;
                    float rg = sigm(gir[c] + gacc[0][i][r] + bhr[q]);
                    float zg = sigm(gir[H + c] + gacc[1][i][r] + bhz[q]);
                    float ng = tanhf(gir[2 * H + c] + rg * (gacc[2][i][r] + bhn[q]));
                    float hn = (1.f - zg) * ng + zg * hreg[q][i][r];
                    hreg[q][i][r] = hn;
                    scs_h[slotr * 400 + c] = f2bf(hn);
                }
        }
        __syncthreads();   // all hls reads (A-frags) + scs_h writes complete
        // copy new h: scs_h -> hls (strided) and hall (global, for vocab GEMM)
        for (int i = tid; i < 30 * H; i += 512) {
            int slot = i / H, k = i % H;
            u16 v = scs_h[i];
            hls[slot * HP2 + k] = v;
            hall[((long long)t * NB + slot * 16 + b) * H + k] = v;
        }
        __syncthreads();

        // ---- P1: scores[slot][s] = h . E[b][s]  (M=32, N=256, K=400) ----
        {
            const int nt0 = w * 2;
            f32x4 acc[2][2];
#pragma unroll
            for (int i = 0; i < 2; ++i)
#pragma unroll
                for (int jj = 0; jj < 2; ++jj) acc[i][jj] = (f32x4){0.f, 0.f, 0.f, 0.f};
            const u16* br0 = Eb + ((long long)b * S + nt0 * 16 + fr) * H + kq * 8;
            const u16* br1 = Eb + ((long long)b * S + (nt0 + 1) * 16 + fr) * H + kq * 8;
            const u16* ar0 = hls + fr * HP2 + kq * 8;
            const u16* ar1 = hls + (16 + fr) * HP2 + kq * 8;
#pragma unroll
            for (int kk = 0; kk < 13; ++kk) {
                bf16x8 av0 = *(const bf16x8*)(ar0 + kk * 32);
                bf16x8 av1 = *(const bf16x8*)(ar1 + kk * 32);
                bf16x8 bv0, bv1;
                if (kk == 12 && kq >= 2) {
                    bv0 = (bf16x8){0,0,0,0,0,0,0,0}; bv1 = bv0;
                } else {
                    bv0 = *(const bf16x8*)(br0 + kk * 32);
                    bv1 = *(const bf16x8*)(br1 + kk * 32);
                }
                acc[0][0] = __builtin_amdgcn_mfma_f32_16x16x32_bf16(av0, bv0, acc[0][0], 0, 0, 0);
                acc[1][0] = __builtin_amdgcn_mfma_f32_16x16x32_bf16(av1, bv0, acc[1][0], 0, 0, 0);
                acc[0][1] = __builtin_amdgcn_mfma_f32_16x16x32_bf16(av0, bv1, acc[0][1], 0, 0, 0);
                acc[1][1] = __builtin_amdgcn_mfma_f32_16x16x32_bf16(av1, bv1, acc[1][1], 0, 0, 0);
            }
#pragma unroll
            for (int i = 0; i < 2; ++i)
#pragma unroll
                for (int jj = 0; jj < 2; ++jj)
#pragma unroll
                    for (int r = 0; r < 4; ++r)
                        scs[(i * 16 + kq * 4 + r) * SCP + (nt0 + jj) * 16 + fr] = acc[i][jj][r];
        }
        __syncthreads();

        // ---- P2: softmax rows ----
        for (int i = 0; i < 4; ++i) {
            int row = w * 4 + i;
            if (row >= 30) break;
            int n = row * 16 + b;
            float v[4];
            float mx = -3.0e38f;
#pragma unroll
            for (int q = 0; q < 4; ++q) {
                int s = lane + 64 * q;
                float x = (s < len) ? scs[row * SCP + s] : -3.0e38f;
                v[q] = x; mx = fmaxf(mx, x);
            }
            mx = fmaxf(mx, __shfl_xor(mx, 1));  mx = fmaxf(mx, __shfl_xor(mx, 2));
            mx = fmaxf(mx, __shfl_xor(mx, 4));  mx = fmaxf(mx, __shfl_xor(mx, 8));
            mx = fmaxf(mx, __shfl_xor(mx, 16)); mx = fmaxf(mx, __shfl_xor(mx, 32));
            float sum = 0.f;
#pragma unroll
            for (int q = 0; q < 4; ++q) {
                int s = lane + 64 * q;
                float e = (s < len) ? __expf(v[q] - mx) : 0.f;
                v[q] = e; sum += e;
            }
            sum += __shfl_xor(sum, 1);  sum += __shfl_xor(sum, 2);
            sum += __shfl_xor(sum, 4);  sum += __shfl_xor(sum, 8);
            sum += __shfl_xor(sum, 16); sum += __shfl_xor(sum, 32);
            float inv = 1.f / sum;
#pragma unroll
            for (int q = 0; q < 4; ++q) {
                int s = lane + 64 * q;
                float pr = v[q] * inv;
                pls[row * PP + s] = f2bf(pr);
                probfT[((long long)(t * NB + n)) * S + s] = pr;
            }
        }
        __syncthreads();

        // ---- P3: ctx[slot][k] = sum_s prob[slot][s] * ET[b][k][s] ----
        for (int nt = w; nt < 25; nt += 8) {
            f32x4 acc0 = (f32x4){0.f,0.f,0.f,0.f}, acc1 = (f32x4){0.f,0.f,0.f,0.f};
            const u16* brow = ETb + ((long long)b * H + nt * 16 + fr) * S + kq * 8;
            const u16* ar0 = pls + fr * PP + kq * 8;
            const u16* ar1 = pls + (16 + fr) * PP + kq * 8;
#pragma unroll
            for (int kk = 0; kk < 8; ++kk) {
                bf16x8 bv  = *(const bf16x8*)(brow + kk * 32);
                bf16x8 av0 = *(const bf16x8*)(ar0 + kk * 32);
                bf16x8 av1 = *(const bf16x8*)(ar1 + kk * 32);
                acc0 = __builtin_amdgcn_mfma_f32_16x16x32_bf16(av0, bv, acc0, 0, 0, 0);
                acc1 = __builtin_amdgcn_mfma_f32_16x16x32_bf16(av1, bv, acc1, 0, 0, 0);
            }
#pragma unroll
            for (int r = 0; r < 4; ++r) {
                cxs[(kq * 4 + r) * CXP + nt * 16 + fr] = acc0[r];
                cxs[(16 + kq * 4 + r) * CXP + nt * 16 + fr] = acc1[r];
            }
        }
        __syncthreads();

        // ---- P4: p_gen switch (+ gate at t==0) ----
        for (int i = 0; i < 4; ++i) {
            int slot = w + 8 * i;
            if (slot >= 30) break;
            int n = slot * 16 + b;
            const u16* xrow = decinb + ((long long)t * NB + n) * H;
            float p = 0.f;
            for (int k = lane; k < H; k += 64)
                p += bf2f(hls[slot * HP2 + k]) * Wr[k]
                   + cxs[slot * CXP + k] * Wr[H + k]
                   + bf2f(xrow[k]) * Wr[2 * H + k];
            p += __shfl_xor(p, 1);  p += __shfl_xor(p, 2);
            p += __shfl_xor(p, 4);  p += __shfl_xor(p, 8);
            p += __shfl_xor(p, 16); p += __shfl_xor(p, 32);
            if (lane == 0) swvT[t * NB + n] = sigm(p + br[0]);
            if (t == 0) {
                for (int g = 0; g < G; ++g) {
                    float qv = 0.f;
                    for (int k = lane; k < H; k += 64)
                        qv += cxs[slot * CXP + k] * Wg[g * H + k];
                    qv += __shfl_xor(qv, 1);  qv += __shfl_xor(qv, 2);
                    qv += __shfl_xor(qv, 4);  qv += __shfl_xor(qv, 8);
                    qv += __shfl_xor(qv, 16); qv += __shfl_xor(qv, 32);
                    if (lane == 0) gout[(long long)n * G + g] = qv + bg[g];
                }
            }
        }
        __syncthreads();   // scs/pls/cxs reuse next iteration
    }
}

// scale all t at once: out[n][t][:] *= sw[t][n] / rowsum[t*NB+n]
__global__ void scale_all_kernel(float* __restrict__ out, const float* __restrict__ swvT,
                                 const float* __restrict__ rowsumT) {
    const int n = blockIdx.x;
    const int col = blockIdx.y * 256 + threadIdx.x;
    if (col >= V) return;
#pragma unroll
    for (int t = 0; t < T; ++t) {
        float f = swvT[t * NB + n] / rowsumT[t * NB + n];
        out[((long long)n * T + t) * V + col] *= f;
    }
}

__global__ void scatter_all_kernel(float* __restrict__ out, const int* __restrict__ story,
                                   const int* __restrict__ lens, const float* __restrict__ swvT,
                                   const float* __restrict__ probfT) {
    const int n = blockIdx.x, t = blockIdx.y, b = n & 15, s = threadIdx.x;
    if (s < lens[b]) {
        int tok = story[b * S + s];
        atomicAdd(out + ((long long)n * T + t) * V + tok,
                  (1.f - swvT[t * NB + n]) * probfT[((long long)(t * NB + n)) * S + s]);
    }
}

// ---------------------------------------------------------------------------
extern "C" void kernel_launch(void* const* d_in, const int* in_sizes, int n_in,
                              void* d_out, int out_size, void* d_ws, size_t ws_size,
                              hipStream_t stream) {
    const int*   story = (const int*)d_in[0];
    const int*   lens  = (const int*)d_in[1];
    const int*   tgt   = (const int*)d_in[2];
    const int*   dom   = (const int*)d_in[3];
    const int*   sidx  = (const int*)d_in[4];
    const float* emb   = (const float*)d_in[5];
    const float* wihf  = (const float*)d_in[6];
    const float* whhf  = (const float*)d_in[7];
    const float* bihf  = (const float*)d_in[8];
    const float* bhhf  = (const float*)d_in[9];
    const float* wihb  = (const float*)d_in[10];
    const float* whhb  = (const float*)d_in[11];
    const float* bihb  = (const float*)d_in[12];
    const float* bhhb  = (const float*)d_in[13];
    const float* dwih  = (const float*)d_in[14];
    const float* dwhh  = (const float*)d_in[15];
    const float* dbih  = (const float*)d_in[16];
    const float* dbhh  = (const float*)d_in[17];
    const float* Wr    = (const float*)d_in[18];
    const float* br    = (const float*)d_in[19];
    const float* Wg    = (const float*)d_in[20];
    const float* bg    = (const float*)d_in[21];
    const float* slt   = (const float*)d_in[22];
    float* out = (float*)d_out;

    char* wsb = (char*)d_ws;
    size_t off = 0;
    auto alloc = [&](size_t bytes) -> char* {
        char* p = wsb + off;
        off += (bytes + 255) & ~(size_t)255;
        return p;
    };
    u16*   embb   = (u16*)alloc((size_t)V * H * 2);
    u16*   wihfb  = (u16*)alloc((size_t)H3 * H * 2);
    u16*   wihbb  = (u16*)alloc((size_t)H3 * H * 2);
    u16*   dwihb  = (u16*)alloc((size_t)H3 * H * 2);
    u16*   dwhhb  = (u16*)alloc((size_t)H3 * H * 2);
    u16*   wencp  = (u16*)alloc((size_t)2 * ENBLK * EROWS * EKP * 2);
    unsigned* hbuf = (unsigned*)alloc((size_t)2 * S * B * EKP * 4);   // 13.6 MB rotating
    int*   flags  = (int*)alloc((size_t)2 * S * ENBLK * 4);           // 40 KB rotating
    u16*   xb     = (u16*)alloc((size_t)S * B * H * 2);
    u16*   decinb = (u16*)alloc((size_t)T * NB * H * 2);
    float* gif    = (float*)alloc((size_t)S * B * H3 * 4);
    float* gib    = (float*)alloc((size_t)S * B * H3 * 4);
    float* dgi    = (float*)alloc((size_t)T * NB * H3 * 4);
    float* ysf    = (float*)alloc((size_t)B * S * H * 4);
    float* ysb    = (float*)alloc((size_t)B * S * H * 4);
    float* hfv    = (float*)alloc((size_t)B * H * 4);
    float* hbv    = (float*)alloc((size_t)B * H * 4);
    u16*   Eb     = (u16*)alloc((size_t)B * S * H * 2);
    u16*   ETb    = (u16*)alloc((size_t)B * H * S * 2);
    u16*   hall   = (u16*)alloc((size_t)T * NB * H * 2);
    float* probfT = (float*)alloc((size_t)T * NB * S * 4);
    float* swvT   = (float*)alloc((size_t)T * NB * 4);
    float* rowsumT = (float*)alloc((size_t)T * NB * 4);
    (void)ws_size; (void)in_sizes; (void)n_in; (void)out_size;

    auto launch_gemm = [&](const u16* A, const u16* Bt, const float* bias, float* C,
                           int M, int N, int K, int lda, int ldb, long long ldc,
                           long long sA, long long sB, long long sC, int nb,
                           int mode, float* rs) {
        dim3 g((M + 63) / 64, (N + 63) / 64, nb);
        gemm_bt<<<g, 256, 0, stream>>>(A, Bt, bias, C, M, N, K, lda, ldb, ldc,
                                       sA, sB, sC, mode, rs);
    };

    hipFuncSetAttribute((const void*)decoder_persist_kernel,
                        hipFuncAttributeMaxDynamicSharedMemorySize, FUSED_LDS);

    // ---- setup: casts, embeddings, input-side GEMMs -----------------------
    cvt_bf16_kernel<<<2048, 256, 0, stream>>>(emb, embb, V * H);
    cvt4_kernel<<<1024, 256, 0, stream>>>(wihf, wihb, dwih, dwhh,
                                          wihfb, wihbb, dwihb, dwhhb, H3 * H);
    {
        const int total = 2 * ENBLK * EROWS * EKP;
        prep_wenc_kernel<<<(total + 255) / 256, 256, 0, stream>>>(whhf, whhb, wencp);
    }
    embed_story_kernel<<<S * B, 256, 0, stream>>>(story, embb, xb);
    { dim3 g(NB, T); build_decin_kernel<<<g, 256, 0, stream>>>(tgt, dom, sidx, slt, embb, decinb); }

    launch_gemm(xb, wihfb, bihf, gif, S * B, H3, H, H, H, H3, 0, 0, 0, 1, 0, nullptr);
    launch_gemm(xb, wihbb, bihb, gib, S * B, H3, H, H, H, H3, 0, 0, 0, 1, 0, nullptr);
    launch_gemm(decinb, dwihb, dbih, dgi, T * NB, H3, H, H, H, H3, 0, 0, 0, 1, 0, nullptr);

    // ---- encoder recurrence (R8 protocol) ---------------------------------
    hipMemsetAsync(flags, 0, (size_t)2 * S * ENBLK * 4, stream);
    hipMemsetAsync(hbuf, 0, (size_t)2 * S * B * EKP * 4, stream);
    hipMemsetAsync(rowsumT, 0, (size_t)T * NB * 4, stream);
    enc_rnn2_kernel<<<2 * ENBLK, 256, 0, stream>>>(wencp, bhhf, bhhb, gif, gib, lens,
                                                   hbuf, flags, ysf, ysb, hfv, hbv);
    { dim3 g(B, S / 32); packE_kernel<<<g, 256, 0, stream>>>(ysf, ysb, Eb, ETb); }

    // ---- decoder: single persistent launch --------------------------------
    decoder_persist_kernel<<<16, 512, FUSED_LDS, stream>>>(
        dgi, dwhhb, dbhh, hfv, hbv, hall, decinb, Eb, ETb, lens,
        Wr, br, Wg, bg, probfT, swvT, out + (size_t)NB * T * V);

    // ---- batched vocab projection: one GEMM over all (t, n) rows ----------
    launch_gemm(hall, embb, nullptr, out, T * NB, V, H, H, H, V,
                0, 0, 0, 1, 2, rowsumT);
    { dim3 g(NB, (V + 255) / 256); scale_all_kernel<<<g, 256, 0, stream>>>(out, swvT, rowsumT); }
    { dim3 g(NB, T); scatter_all_kernel<<<g, 256, 0, stream>>>(out, story, lens, swvT, probfT); }
}

// Round 11
// 2424.338 us; speedup vs baseline: 1.2935x; 1.2180x over previous
//
#include <hip/hip_runtime.h>
#include <hip/hip_bf16.h>

typedef unsigned short u16;
typedef __attribute__((ext_vector_type(8))) short bf16x8;
typedef __attribute__((ext_vector_type(4))) float f32x4;
typedef __attribute__((ext_vector_type(4))) unsigned u32x4;

static constexpr int V = 20000, H = 400, B = 16, S = 256, NSLOT = 30, T = 10, G = 3;
static constexpr int H3 = 3 * H;           // 1200
static constexpr int NB = NSLOT * B;       // 480
static constexpr int MM = T * NB;          // 4800 vocab-GEMM rows
// encoder partition (R8 protocol — best measured)
static constexpr int ENBLK = 20;           // blocks per direction
static constexpr int ESL   = 20;           // h components per block (400/20)
static constexpr int EROWS = 64;           // padded weight rows per block
static constexpr int EKP   = 416;          // padded K
// fused decoder LDS strides
static constexpr int HP2 = 424;            // h_lds row stride (u16)
static constexpr int SCP = 260;            // scores row stride (f32)
static constexpr int PP  = 264;            // prob row stride (u16)
static constexpr int CXP = 404;            // ctx row stride (f32)
static constexpr int FUSED_LDS = 32*HP2*2 + 32*SCP*4 + 32*PP*2 + 32*CXP*4; // 129024

__device__ __forceinline__ float bf2f(u16 v) {
    union { unsigned u; float f; } x; x.u = ((unsigned)v) << 16; return x.f;
}
__device__ __forceinline__ u16 f2bf(float f) {
    union { float f; unsigned u; } x; x.f = f;
    unsigned r = x.u + 0x7fffu + ((x.u >> 16) & 1u);   // round-to-nearest-even
    return (u16)(r >> 16);
}
__device__ __forceinline__ float sigm(float v) { return 1.f / (1.f + __expf(-v)); }

// ---------------------------------------------------------------------------
// Generic batched GEMM: C[m][n] = sum_k A[m][k] * Bt[n][k]  (+bias[n])
// mode 0: plain (+bias). mode 1: C=exp(acc)+rowsum, ldc layout.
// ---------------------------------------------------------------------------
__global__ __launch_bounds__(256) void gemm_bt(
    const u16* __restrict__ A, const u16* __restrict__ Bt,
    const float* __restrict__ bias, float* __restrict__ C,
    int M, int N, int K, int lda, int ldb, long long ldc,
    long long sA, long long sB, long long sC,
    int mode, float* __restrict__ rowsum)
{
    __shared__ u16 As[64][40];
    __shared__ u16 Bs[64][40];
    const int bz = blockIdx.z;
    A  += (long long)bz * sA;
    Bt += (long long)bz * sB;
    C  += (long long)bz * sC;
    const int m0 = blockIdx.x * 64, n0 = blockIdx.y * 64;
    const int tid = threadIdx.x, wave = tid >> 6, lane = tid & 63;
    const int wm = (wave >> 1) * 32, wn = (wave & 1) * 32;
    const int srow = tid >> 2, scol = (tid & 3) * 8;
    const int fr = lane & 15, kq = lane >> 4;
    f32x4 acc[2][2];
#pragma unroll
    for (int i = 0; i < 2; ++i)
#pragma unroll
        for (int j = 0; j < 2; ++j) acc[i][j] = (f32x4){0.f, 0.f, 0.f, 0.f};

    for (int k0 = 0; k0 < K; k0 += 32) {
        {
            int gr = m0 + srow, gc = k0 + scol;
            bf16x8 v;
            if (gr < M && gc + 8 <= K) {
                v = *(const bf16x8*)(A + (long long)gr * lda + gc);
            } else {
                short tmp[8];
#pragma unroll
                for (int j = 0; j < 8; ++j)
                    tmp[j] = (gr < M && gc + j < K) ? (short)A[(long long)gr * lda + gc + j] : (short)0;
                v = *(bf16x8*)tmp;
            }
            *(bf16x8*)&As[srow][scol] = v;
        }
        {
            int gr = n0 + srow, gc = k0 + scol;
            bf16x8 v;
            if (gr < N && gc + 8 <= K) {
                v = *(const bf16x8*)(Bt + (long long)gr * ldb + gc);
            } else {
                short tmp[8];
#pragma unroll
                for (int j = 0; j < 8; ++j)
                    tmp[j] = (gr < N && gc + j < K) ? (short)Bt[(long long)gr * ldb + gc + j] : (short)0;
                v = *(bf16x8*)tmp;
            }
            *(bf16x8*)&Bs[srow][scol] = v;
        }
        __syncthreads();
        bf16x8 af[2], bfr[2];
#pragma unroll
        for (int i = 0; i < 2; ++i) af[i]  = *(const bf16x8*)&As[wm + i * 16 + fr][kq * 8];
#pragma unroll
        for (int j = 0; j < 2; ++j) bfr[j] = *(const bf16x8*)&Bs[wn + j * 16 + fr][kq * 8];
#pragma unroll
        for (int i = 0; i < 2; ++i)
#pragma unroll
            for (int j = 0; j < 2; ++j)
                acc[i][j] = __builtin_amdgcn_mfma_f32_16x16x32_bf16(af[i], bfr[j], acc[i][j], 0, 0, 0);
        __syncthreads();
    }

#pragma unroll
    for (int i = 0; i < 2; ++i)
#pragma unroll
        for (int j = 0; j < 2; ++j) {
            int col = n0 + wn + j * 16 + fr;
            float bv = (bias != nullptr && col < N) ? bias[col] : 0.f;
#pragma unroll
            for (int r = 0; r < 4; ++r) {
                int row = m0 + wm + i * 16 + kq * 4 + r;
                bool ok = (row < M) && (col < N);
                float v = acc[i][j][r] + bv;
                if (mode >= 1) { v = ok ? __expf(v) : 0.f; acc[i][j][r] = v; }
                if (ok) C[(long long)row * ldc + col] = v;
            }
        }
    if (mode >= 1) {
#pragma unroll
        for (int i = 0; i < 2; ++i)
#pragma unroll
            for (int r = 0; r < 4; ++r) {
                float s = acc[i][0][r] + acc[i][1][r];
                s += __shfl_xor(s, 1); s += __shfl_xor(s, 2);
                s += __shfl_xor(s, 4); s += __shfl_xor(s, 8);
                if (fr == 0) {
                    int row = m0 + wm + i * 16 + kq * 4 + r;
                    if (row < M) atomicAdd(&rowsum[row], s);
                }
            }
    }
}

// ---------------------------------------------------------------------------
// Dedicated 128x128-tile vocab GEMM: A=hall[4800][400], Bt=embb[20000][400].
// C = exp(A.Bt^T) written in out[n][t][v] layout (row = t*NB+n); atomicAdd
// per-row sums into rowsum. 4 waves, each owns a 64x64 quadrant (acc[4][4]).
// Halves L2/L3 panel traffic vs the 64^2 kernel (1.2 GB vs 2.4 GB).
// ---------------------------------------------------------------------------
__global__ __launch_bounds__(256) void vocab_gemm_kernel(
    const u16* __restrict__ A, const u16* __restrict__ Bt,
    float* __restrict__ C, float* __restrict__ rowsum)
{
    __shared__ u16 As[128][40];
    __shared__ u16 Bs[128][40];
    const int m0 = blockIdx.x * 128, n0 = blockIdx.y * 128;
    const int tid = threadIdx.x, wave = tid >> 6, lane = tid & 63;
    const int wm = (wave >> 1) * 64, wn = (wave & 1) * 64;
    const int srow = tid >> 1, scol = (tid & 1) * 16;
    const int fr = lane & 15, kq = lane >> 4;
    f32x4 acc[4][4];
#pragma unroll
    for (int i = 0; i < 4; ++i)
#pragma unroll
        for (int j = 0; j < 4; ++j) acc[i][j] = (f32x4){0.f, 0.f, 0.f, 0.f};

    for (int k0 = 0; k0 < H; k0 += 32) {
        {   // stage A: thread stages 16 elems of row srow
            int gr = m0 + srow, gc = k0 + scol;
            bf16x8 v0 = (bf16x8){0,0,0,0,0,0,0,0}, v1 = v0;
            if (gr < MM) {
                const u16* src = A + (long long)gr * H + gc;
                if (gc + 8 <= H)  v0 = *(const bf16x8*)src;
                if (gc + 16 <= H) v1 = *(const bf16x8*)(src + 8);
            }
            *(bf16x8*)&As[srow][scol] = v0;
            *(bf16x8*)&As[srow][scol + 8] = v1;
        }
        {   // stage B
            int gr = n0 + srow, gc = k0 + scol;
            bf16x8 v0 = (bf16x8){0,0,0,0,0,0,0,0}, v1 = v0;
            if (gr < V) {
                const u16* src = Bt + (long long)gr * H + gc;
                if (gc + 8 <= H)  v0 = *(const bf16x8*)src;
                if (gc + 16 <= H) v1 = *(const bf16x8*)(src + 8);
            }
            *(bf16x8*)&Bs[srow][scol] = v0;
            *(bf16x8*)&Bs[srow][scol + 8] = v1;
        }
        __syncthreads();
        bf16x8 af[4], bfr[4];
#pragma unroll
        for (int i = 0; i < 4; ++i) af[i]  = *(const bf16x8*)&As[wm + i * 16 + fr][kq * 8];
#pragma unroll
        for (int j = 0; j < 4; ++j) bfr[j] = *(const bf16x8*)&Bs[wn + j * 16 + fr][kq * 8];
#pragma unroll
        for (int i = 0; i < 4; ++i)
#pragma unroll
            for (int j = 0; j < 4; ++j)
                acc[i][j] = __builtin_amdgcn_mfma_f32_16x16x32_bf16(af[i], bfr[j], acc[i][j], 0, 0, 0);
        __syncthreads();
    }

    // epilogue: exp + mode-2 scatter layout (row = t*NB+n -> out[n][t][col])
#pragma unroll
    for (int i = 0; i < 4; ++i)
#pragma unroll
        for (int j = 0; j < 4; ++j)
#pragma unroll
            for (int r = 0; r < 4; ++r) {
                int row = m0 + wm + i * 16 + kq * 4 + r;
                int col = n0 + wn + j * 16 + fr;
                bool ok = (row < MM) && (col < V);
                float v = ok ? __expf(acc[i][j][r]) : 0.f;
                acc[i][j][r] = v;
                if (ok) {
                    int n = row % NB, t = row / NB;
                    C[((long long)n * T + t) * V + col] = v;
                }
            }
#pragma unroll
    for (int i = 0; i < 4; ++i)
#pragma unroll
        for (int r = 0; r < 4; ++r) {
            float s = acc[i][0][r] + acc[i][1][r] + acc[i][2][r] + acc[i][3][r];
            s += __shfl_xor(s, 1); s += __shfl_xor(s, 2);
            s += __shfl_xor(s, 4); s += __shfl_xor(s, 8);
            if (fr == 0) {
                int row = m0 + wm + i * 16 + kq * 4 + r;
                if (row < MM) atomicAdd(&rowsum[row], s);
            }
        }
}

// ---------------------------------------------------------------------------
// small utility kernels
// ---------------------------------------------------------------------------
__global__ void cvt_bf16_kernel(const float* __restrict__ src, u16* __restrict__ dst, int n) {
    for (int i = blockIdx.x * blockDim.x + threadIdx.x; i < n; i += gridDim.x * blockDim.x)
        dst[i] = f2bf(src[i]);
}

__global__ void cvt4_kernel(const float* __restrict__ a, const float* __restrict__ b,
                            const float* __restrict__ c, const float* __restrict__ d,
                            u16* __restrict__ da, u16* __restrict__ db,
                            u16* __restrict__ dc, u16* __restrict__ dd, int n) {
    for (int i = blockIdx.x * blockDim.x + threadIdx.x; i < n; i += gridDim.x * blockDim.x) {
        da[i] = f2bf(a[i]); db[i] = f2bf(b[i]); dc[i] = f2bf(c[i]); dd[i] = f2bf(d[i]);
    }
}

// weight prep for the distributed encoder: dst[dir][j][rloc][k], rloc = g*20+c
__global__ void prep_wenc_kernel(const float* __restrict__ whhf, const float* __restrict__ whhb,
                                 u16* __restrict__ dst) {
    int idx = blockIdx.x * 256 + threadIdx.x;
    const int total = 2 * ENBLK * EROWS * EKP;
    if (idx >= total) return;
    int k = idx % EKP; int r = idx / EKP;
    int rloc = r % EROWS; r /= EROWS;
    int j = r % ENBLK; int dir = r / ENBLK;
    u16 v = 0;
    if (k < H && rloc < 3 * ESL) {
        int g = rloc / ESL, c = rloc % ESL;
        const float* W = dir ? whhb : whhf;
        v = f2bf(W[(long long)(g * H + j * ESL + c) * H + k]);
    }
    dst[idx] = v;
}

__global__ void embed_story_kernel(const int* __restrict__ story, const u16* __restrict__ embb,
                                   u16* __restrict__ xb) {
    int row = blockIdx.x;                 // row = s*16 + b
    int s = row >> 4, b = row & 15;
    int tok = story[b * S + s];
    const u16* e = embb + (long long)tok * H;
    u16* d = xb + (long long)row * H;
    for (int k = threadIdx.x; k < H; k += blockDim.x) d[k] = e[k];
}

__global__ void build_decin_kernel(const int* __restrict__ tgt, const int* __restrict__ dom,
                                   const int* __restrict__ sidx, const float* __restrict__ slt,
                                   const u16* __restrict__ embb, u16* __restrict__ decin) {
    int n = blockIdx.x, t = blockIdx.y;
    int b = n & 15, slot = n >> 4;
    u16* d = decin + ((long long)t * NB + n) * H;
    if (t == 0) {
        const float* s1 = slt + (long long)dom[slot] * H;
        const float* s2 = slt + (long long)sidx[slot] * H;
        for (int k = threadIdx.x; k < H; k += blockDim.x) d[k] = f2bf(s1[k] + s2[k]);
    } else {
        int tok = tgt[(b * NSLOT + slot) * T + (t - 1)];
        const u16* e = embb + (long long)tok * H;
        for (int k = threadIdx.x; k < H; k += blockDim.x) d[k] = e[k];
    }
}

// ---------------------------------------------------------------------------
// Distributed encoder recurrence — R8 protocol v6 VERBATIM (best measured).
// ---------------------------------------------------------------------------
__global__ __launch_bounds__(256) void enc_rnn2_kernel(
    const u16* __restrict__ wencp,
    const float* __restrict__ bhhf, const float* __restrict__ bhhb,
    const float* __restrict__ gif, const float* __restrict__ gib,
    const int* __restrict__ lens,
    unsigned* __restrict__ hbuf, int* __restrict__ flags,
    float* __restrict__ ysf, float* __restrict__ ysb,
    float* __restrict__ hfo, float* __restrict__ hbo)
{
    const int bid = blockIdx.x;
    const int dir = bid / ENBLK, j = bid % ENBLK;
    const float* bhh = dir ? bhhb : bhhf;
    const float* gi  = dir ? gib  : gif;
    float* ys = dir ? ysb : ysf;
    float* ho = dir ? hbo : hfo;

    __shared__ u16 wlds[EROWS * EKP];      // 53248 B
    __shared__ float ghs[EROWS * 17];      // 4352 B

    const int tid = threadIdx.x, wave = tid >> 6, lane = tid & 63;
    const int fr = lane & 15, kq = lane >> 4;

    const u16* wsrc = wencp + (long long)(dir * ENBLK + j) * EROWS * EKP;
    for (int i = tid * 8; i < EROWS * EKP; i += 256 * 8)
        *(bf16x8*)&wlds[i] = *(const bf16x8*)&wsrc[i];
    for (int i = tid; i < EROWS * 17; i += 256) ghs[i] = 0.f;

    const int p0 = tid, p1 = 256 + tid;
    const bool has1 = (tid < 64);
    const int b0 = p0 / ESL, kl0 = p0 % ESL;
    const int b1 = has1 ? p1 / ESL : 0, kl1 = has1 ? p1 % ESL : 0;
    const int k0 = j * ESL;
    const int len0 = lens[b0];
    const int len1 = has1 ? lens[b1] : 0;
    const float bhr0 = bhh[k0 + kl0], bhz0 = bhh[H + k0 + kl0], bhn0 = bhh[2 * H + k0 + kl0];
    const float bhr1 = has1 ? bhh[k0 + kl1] : 0.f;
    const float bhz1 = has1 ? bhh[H + k0 + kl1] : 0.f;
    const float bhn1 = has1 ? bhh[2 * H + k0 + kl1] : 0.f;
    float h0r = 0.f, h1r = 0.f;

    unsigned* hb_d = hbuf + (long long)dir * S * B * EKP;
    int* flg_d = flags + dir * S * ENBLK;
    const u16* arow = &wlds[(wave * 16 + fr) * EKP + kq * 8];
    __syncthreads();

    for (int t = 0; t < S; ++t) {
        const int s = dir ? (S - 1 - t) : t;
        const float* gbase = gi + (long long)s * B * H3;
        float gr0 = gbase[b0 * H3 + k0 + kl0];
        float gz0 = gbase[b0 * H3 + H + k0 + kl0];
        float gn0 = gbase[b0 * H3 + 2 * H + k0 + kl0];
        float gr1 = 0.f, gz1 = 0.f, gn1 = 0.f;
        if (has1) {
            gr1 = gbase[b1 * H3 + k0 + kl1];
            gz1 = gbase[b1 * H3 + H + k0 + kl1];
            gn1 = gbase[b1 * H3 + 2 * H + k0 + kl1];
        }

        f32x4 acc = (f32x4){0.f, 0.f, 0.f, 0.f};
        if (t > 0) {
            const int* fl = flg_d + (t - 1) * ENBLK;
            for (;;) {
                int v = 1;
                if (lane < ENBLK)
                    v = __hip_atomic_load(&fl[lane], __ATOMIC_RELAXED,
                                          __HIP_MEMORY_SCOPE_AGENT);
                if (__all(v != 0)) break;
                __builtin_amdgcn_s_sleep(2);
            }
            asm volatile("" ::: "memory");   // keep hbuf reads after the poll
            const unsigned* hrow = hb_d + ((long long)(t - 1) * B + fr) * EKP + kq * 8;
            f32x4 acch = (f32x4){0.f, 0.f, 0.f, 0.f};
            f32x4 accl = (f32x4){0.f, 0.f, 0.f, 0.f};
#pragma unroll
            for (int kk = 0; kk < 13; ++kk) {
                u32x4 a = *(const u32x4*)(hrow + kk * 32);
                u32x4 b = *(const u32x4*)(hrow + kk * 32 + 4);
                union { unsigned u[4]; bf16x8 v; } hi, lo;
                hi.u[0] = __builtin_amdgcn_perm(a[1], a[0], 0x05040100u);
                hi.u[1] = __builtin_amdgcn_perm(a[3], a[2], 0x05040100u);
                hi.u[2] = __builtin_amdgcn_perm(b[1], b[0], 0x05040100u);
                hi.u[3] = __builtin_amdgcn_perm(b[3], b[2], 0x05040100u);
                lo.u[0] = __builtin_amdgcn_perm(a[1], a[0], 0x07060302u);
                lo.u[1] = __builtin_amdgcn_perm(a[3], a[2], 0x07060302u);
                lo.u[2] = __builtin_amdgcn_perm(b[1], b[0], 0x07060302u);
                lo.u[3] = __builtin_amdgcn_perm(b[3], b[2], 0x07060302u);
                bf16x8 av = *(const bf16x8*)(arow + kk * 32);
                acch = __builtin_amdgcn_mfma_f32_16x16x32_bf16(av, hi.v, acch, 0, 0, 0);
                accl = __builtin_amdgcn_mfma_f32_16x16x32_bf16(av, lo.v, accl, 0, 0, 0);
            }
            acc = acch + accl;
        }
#pragma unroll
        for (int r = 0; r < 4; ++r) ghs[(wave * 16 + kq * 4 + r) * 17 + fr] = acc[r];
        __syncthreads();

        unsigned* hpub = hb_d + (long long)t * B * EKP;
        {
            float ghr = ghs[kl0 * 17 + b0];
            float ghz = ghs[(ESL + kl0) * 17 + b0];
            float ghn = ghs[(2 * ESL + kl0) * 17 + b0];
            float rg = sigm(gr0 + ghr + bhr0);
            float zg = sigm(gz0 + ghz + bhz0);
            float ng = tanhf(gn0 + rg * (ghn + bhn0));
            float hn = (1.f - zg) * ng + zg * h0r;
            bool msk = s < len0;
            float y = msk ? hn : 0.f;
            if (msk) h0r = hn;
            ys[((long long)(b0 * S + s)) * H + k0 + kl0] = y;
            u16 hi = f2bf(h0r);
            unsigned packed = (unsigned)hi | ((unsigned)f2bf(h0r - bf2f(hi)) << 16);
            __hip_atomic_store(&hpub[b0 * EKP + k0 + kl0], packed, __ATOMIC_RELAXED,
                               __HIP_MEMORY_SCOPE_AGENT);
        }
        if (has1) {
            float ghr = ghs[kl1 * 17 + b1];
            float ghz = ghs[(ESL + kl1) * 17 + b1];
            float ghn = ghs[(2 * ESL + kl1) * 17 + b1];
            float rg = sigm(gr1 + ghr + bhr1);
            float zg = sigm(gz1 + ghz + bhz1);
            float ng = tanhf(gn1 + rg * (ghn + bhn1));
            float hn = (1.f - zg) * ng + zg * h1r;
            bool msk = s < len1;
            float y = msk ? hn : 0.f;
            if (msk) h1r = hn;
            ys[((long long)(b1 * S + s)) * H + k0 + kl1] = y;
            u16 hi = f2bf(h1r);
            unsigned packed = (unsigned)hi | ((unsigned)f2bf(h1r - bf2f(hi)) << 16);
            __hip_atomic_store(&hpub[b1 * EKP + k0 + kl1], packed, __ATOMIC_RELAXED,
                               __HIP_MEMORY_SCOPE_AGENT);
        }
        __syncthreads();
        if (tid == 0)
            __hip_atomic_store(&flg_d[t * ENBLK + j], 1, __ATOMIC_RELAXED,
                               __HIP_MEMORY_SCOPE_AGENT);
    }
    ho[b0 * H + k0 + kl0] = h0r;
    if (has1) ho[b1 * H + k0 + kl1] = h1r;
}

// E = ys_f + ys_b (bf16, [b][s][k]) and ET (bf16, [b][k][s])
__global__ void packE_kernel(const float* __restrict__ ysf, const float* __restrict__ ysb,
                             u16* __restrict__ E, u16* __restrict__ ET) {
    __shared__ u16 tile[32][400];
    const int b = blockIdx.x, s0 = blockIdx.y * 32;
    for (int si = 0; si < 32; ++si) {
        const long long base = ((long long)b * S + s0 + si) * H;
        for (int k = threadIdx.x; k < H; k += blockDim.x) {
            u16 v = f2bf(ysf[base + k] + ysb[base + k]);
            E[base + k] = v;
            tile[si][k] = v;
        }
    }
    __syncthreads();
    for (int idx = threadIdx.x; idx < 32 * H; idx += blockDim.x) {
        int k = idx >> 5, si = idx & 31;
        ET[((long long)b * H + k) * S + s0 + si] = tile[si][k];
    }
}

__global__ void h0_kernel(const float* __restrict__ hf, const float* __restrict__ hb,
                          float* __restrict__ hf32, u16* __restrict__ hnk) {
    int n = blockIdx.x, b = n & 15;
    for (int k = threadIdx.x; k < H; k += blockDim.x) {
        float v = hf[b * H + k] + hb[b * H + k];
        hf32[(long long)n * H + k] = v;
        hnk[(long long)n * H + k] = f2bf(v);
    }
}

// ---------------------------------------------------------------------------
// Fused decoder step (R8 version): block = batch b (16 blocks, 512 threads).
// ---------------------------------------------------------------------------
__global__ __launch_bounds__(512) void fused_step_kernel(
    const float* __restrict__ dgi, const float* __restrict__ dgh,
    float* __restrict__ hf32, u16* __restrict__ hall,
    const u16* __restrict__ decinb,
    const u16* __restrict__ Eb, const u16* __restrict__ ETb,
    const int* __restrict__ lens,
    const float* __restrict__ Wr, const float* __restrict__ br,
    const float* __restrict__ Wg, const float* __restrict__ bg,
    float* __restrict__ probfT, float* __restrict__ swvT,
    float* __restrict__ gout, int t)
{
    extern __shared__ char smem[];
    u16*   hls = (u16*)smem;                                   // [32][HP2]
    float* scs = (float*)(smem + 32 * HP2 * 2);                // [32][SCP]
    u16*   pls = (u16*)(smem + 32 * HP2 * 2 + 32 * SCP * 4);   // [32][PP]
    float* cxs = (float*)(smem + 32 * HP2 * 2 + 32 * SCP * 4 + 32 * PP * 2); // [32][CXP]

    const int b = blockIdx.x;
    const int tid = threadIdx.x, wave = tid >> 6, lane = tid & 63;
    const int fr = lane & 15, kq = lane >> 4;
    const int len = lens[b];

    for (int i = tid; i < 32 * (HP2 - H); i += 512) {
        int r = i / (HP2 - H), c = H + i % (HP2 - H);
        hls[r * HP2 + c] = 0;
    }
    for (int i = tid; i < 2 * HP2; i += 512) hls[30 * HP2 + i] = 0;
    for (int i = tid; i < 2 * PP; i += 512) pls[30 * PP + i] = 0;

    // P0: GRU cell for the 30 slots of this batch
    for (int i = tid; i < 30 * H; i += 512) {
        int slot = i / H, k = i % H;
        int n = slot * 16 + b;
        const float* gi = dgi + ((long long)t * NB + n) * H3;
        const float* gh = dgh + (long long)n * H3;
        float r  = sigm(gi[k] + gh[k]);
        float z  = sigm(gi[H + k] + gh[H + k]);
        float nn = tanhf(gi[2 * H + k] + r * gh[2 * H + k]);
        float h  = hf32[(long long)n * H + k];
        float hn = (1.f - z) * nn + z * h;
        hf32[(long long)n * H + k] = hn;
        u16 hb = f2bf(hn);
        hall[((long long)t * NB + n) * H + k] = hb;
        hls[slot * HP2 + k] = hb;
    }
    __syncthreads();

    // P1: scores[slot][s] = h . E[b][s]   (M=32, N=256, K=400)
    {
        const int nt0 = wave * 2;
        f32x4 acc[2][2];
#pragma unroll
        for (int i = 0; i < 2; ++i)
#pragma unroll
            for (int jj = 0; jj < 2; ++jj) acc[i][jj] = (f32x4){0.f, 0.f, 0.f, 0.f};
        const u16* br0 = Eb + ((long long)b * S + nt0 * 16 + fr) * H + kq * 8;
        const u16* br1 = Eb + ((long long)b * S + (nt0 + 1) * 16 + fr) * H + kq * 8;
        const u16* ar0 = hls + fr * HP2 + kq * 8;
        const u16* ar1 = hls + (16 + fr) * HP2 + kq * 8;
#pragma unroll
        for (int kk = 0; kk < 13; ++kk) {
            bf16x8 av0 = *(const bf16x8*)(ar0 + kk * 32);
            bf16x8 av1 = *(const bf16x8*)(ar1 + kk * 32);
            bf16x8 bv0, bv1;
            if (kk == 12 && kq >= 2) {
                bv0 = (bf16x8){0,0,0,0,0,0,0,0}; bv1 = bv0;
            } else {
                bv0 = *(const bf16x8*)(br0 + kk * 32);
                bv1 = *(const bf16x8*)(br1 + kk * 32);
            }
            acc[0][0] = __builtin_amdgcn_mfma_f32_16x16x32_bf16(av0, bv0, acc[0][0], 0, 0, 0);
            acc[1][0] = __builtin_amdgcn_mfma_f32_16x16x32_bf16(av1, bv0, acc[1][0], 0, 0, 0);
            acc[0][1] = __builtin_amdgcn_mfma_f32_16x16x32_bf16(av0, bv1, acc[0][1], 0, 0, 0);
            acc[1][1] = __builtin_amdgcn_mfma_f32_16x16x32_bf16(av1, bv1, acc[1][1], 0, 0, 0);
        }
#pragma unroll
        for (int i = 0; i < 2; ++i)
#pragma unroll
            for (int jj = 0; jj < 2; ++jj)
#pragma unroll
                for (int r = 0; r < 4; ++r)
                    scs[(i * 16 + kq * 4 + r) * SCP + (nt0 + jj) * 16 + fr] = acc[i][jj][r];
    }
    __syncthreads();

    // P2: softmax rows
    for (int i = 0; i < 4; ++i) {
        int row = wave * 4 + i;
        if (row >= 30) break;
        int n = row * 16 + b;
        float v[4];
        float mx = -3.0e38f;
#pragma unroll
        for (int q = 0; q < 4; ++q) {
            int s = lane + 64 * q;
            float x = (s < len) ? scs[row * SCP + s] : -3.0e38f;
            v[q] = x; mx = fmaxf(mx, x);
        }
        mx = fmaxf(mx, __shfl_xor(mx, 1));  mx = fmaxf(mx, __shfl_xor(mx, 2));
        mx = fmaxf(mx, __shfl_xor(mx, 4));  mx = fmaxf(mx, __shfl_xor(mx, 8));
        mx = fmaxf(mx, __shfl_xor(mx, 16)); mx = fmaxf(mx, __shfl_xor(mx, 32));
        float sum = 0.f;
#pragma unroll
        for (int q = 0; q < 4; ++q) {
            int s = lane + 64 * q;
            float e = (s < len) ? __expf(v[q] - mx) : 0.f;
            v[q] = e; sum += e;
        }
        sum += __shfl_xor(sum, 1);  sum += __shfl_xor(sum, 2);
        sum += __shfl_xor(sum, 4);  sum += __shfl_xor(sum, 8);
        sum += __shfl_xor(sum, 16); sum += __shfl_xor(sum, 32);
        float inv = 1.f / sum;
#pragma unroll
        for (int q = 0; q < 4; ++q) {
            int s = lane + 64 * q;
            float pr = v[q] * inv;
            pls[row * PP + s] = f2bf(pr);
            probfT[((long long)(t * NB + n)) * S + s] = pr;
        }
    }
    __syncthreads();

    // P3: ctx[slot][k] = sum_s prob[slot][s] * ET[b][k][s]
    for (int nt = wave; nt < 25; nt += 8) {
        f32x4 acc0 = (f32x4){0.f,0.f,0.f,0.f}, acc1 = (f32x4){0.f,0.f,0.f,0.f};
        const u16* brow = ETb + ((long long)b * H + nt * 16 + fr) * S + kq * 8;
        const u16* ar0 = pls + fr * PP + kq * 8;
        const u16* ar1 = pls + (16 + fr) * PP + kq * 8;
#pragma unroll
        for (int kk = 0; kk < 8; ++kk) {
            bf16x8 bv  = *(const bf16x8*)(brow + kk * 32);
            bf16x8 av0 = *(const bf16x8*)(ar0 + kk * 32);
            bf16x8 av1 = *(const bf16x8*)(ar1 + kk * 32);
            acc0 = __builtin_amdgcn_mfma_f32_16x16x32_bf16(av0, bv, acc0, 0, 0, 0);
            acc1 = __builtin_amdgcn_mfma_f32_16x16x32_bf16(av1, bv, acc1, 0, 0, 0);
        }
#pragma unroll
        for (int r = 0; r < 4; ++r) {
            cxs[(kq * 4 + r) * CXP + nt * 16 + fr] = acc0[r];
            cxs[(16 + kq * 4 + r) * CXP + nt * 16 + fr] = acc1[r];
        }
    }
    __syncthreads();

    // P4: p_gen switch (+ gate at t==0)
    for (int i = 0; i < 4; ++i) {
        int slot = wave + 8 * i;
        if (slot >= 30) break;
        int n = slot * 16 + b;
        const u16* xrow = decinb + ((long long)t * NB + n) * H;
        float p = 0.f;
        for (int k = lane; k < H; k += 64)
            p += bf2f(hls[slot * HP2 + k]) * Wr[k]
               + cxs[slot * CXP + k] * Wr[H + k]
               + bf2f(xrow[k]) * Wr[2 * H + k];
        p += __shfl_xor(p, 1);  p += __shfl_xor(p, 2);
        p += __shfl_xor(p, 4);  p += __shfl_xor(p, 8);
        p += __shfl_xor(p, 16); p += __shfl_xor(p, 32);
        if (lane == 0) swvT[t * NB + n] = sigm(p + br[0]);
        if (t == 0) {
            for (int g = 0; g < G; ++g) {
                float q = 0.f;
                for (int k = lane; k < H; k += 64)
                    q += cxs[slot * CXP + k] * Wg[g * H + k];
                q += __shfl_xor(q, 1);  q += __shfl_xor(q, 2);
                q += __shfl_xor(q, 4);  q += __shfl_xor(q, 8);
                q += __shfl_xor(q, 16); q += __shfl_xor(q, 32);
                if (lane == 0) gout[(long long)n * G + g] = q + bg[g];
            }
        }
    }
}

// scale all t at once: out[n][t][:] *= sw[t][n] / rowsum[t*NB+n]
__global__ void scale_all_kernel(float* __restrict__ out, const float* __restrict__ swvT,
                                 const float* __restrict__ rowsumT) {
    const int n = blockIdx.x;
    const int col = blockIdx.y * 256 + threadIdx.x;
    if (col >= V) return;
#pragma unroll
    for (int t = 0; t < T; ++t) {
        float f = swvT[t * NB + n] / rowsumT[t * NB + n];
        out[((long long)n * T + t) * V + col] *= f;
    }
}

__global__ void scatter_all_kernel(float* __restrict__ out, const int* __restrict__ story,
                                   const int* __restrict__ lens, const float* __restrict__ swvT,
                                   const float* __restrict__ probfT) {
    const int n = blockIdx.x, t = blockIdx.y, b = n & 15, s = threadIdx.x;
    if (s < lens[b]) {
        int tok = story[b * S + s];
        atomicAdd(out + ((long long)n * T + t) * V + tok,
                  (1.f - swvT[t * NB + n]) * probfT[((long long)(t * NB + n)) * S + s]);
    }
}

// ---------------------------------------------------------------------------
extern "C" void kernel_launch(void* const* d_in, const int* in_sizes, int n_in,
                              void* d_out, int out_size, void* d_ws, size_t ws_size,
                              hipStream_t stream) {
    const int*   story = (const int*)d_in[0];
    const int*   lens  = (const int*)d_in[1];
    const int*   tgt   = (const int*)d_in[2];
    const int*   dom   = (const int*)d_in[3];
    const int*   sidx  = (const int*)d_in[4];
    const float* emb   = (const float*)d_in[5];
    const float* wihf  = (const float*)d_in[6];
    const float* whhf  = (const float*)d_in[7];
    const float* bihf  = (const float*)d_in[8];
    const float* bhhf  = (const float*)d_in[9];
    const float* wihb  = (const float*)d_in[10];
    const float* whhb  = (const float*)d_in[11];
    const float* bihb  = (const float*)d_in[12];
    const float* bhhb  = (const float*)d_in[13];
    const float* dwih  = (const float*)d_in[14];
    const float* dwhh  = (const float*)d_in[15];
    const float* dbih  = (const float*)d_in[16];
    const float* dbhh  = (const float*)d_in[17];
    const float* Wr    = (const float*)d_in[18];
    const float* br    = (const float*)d_in[19];
    const float* Wg    = (const float*)d_in[20];
    const float* bg    = (const float*)d_in[21];
    const float* slt   = (const float*)d_in[22];
    float* out = (float*)d_out;

    char* wsb = (char*)d_ws;
    size_t off = 0;
    auto alloc = [&](size_t bytes) -> char* {
        char* p = wsb + off;
        off += (bytes + 255) & ~(size_t)255;
        return p;
    };
    u16*   embb   = (u16*)alloc((size_t)V * H * 2);
    u16*   wihfb  = (u16*)alloc((size_t)H3 * H * 2);
    u16*   wihbb  = (u16*)alloc((size_t)H3 * H * 2);
    u16*   dwihb  = (u16*)alloc((size_t)H3 * H * 2);
    u16*   dwhhb  = (u16*)alloc((size_t)H3 * H * 2);
    u16*   wencp  = (u16*)alloc((size_t)2 * ENBLK * EROWS * EKP * 2);
    unsigned* hbuf = (unsigned*)alloc((size_t)2 * S * B * EKP * 4);   // 13.6 MB rotating
    int*   flags  = (int*)alloc((size_t)2 * S * ENBLK * 4);           // 40 KB rotating
    u16*   xb     = (u16*)alloc((size_t)S * B * H * 2);
    u16*   decinb = (u16*)alloc((size_t)T * NB * H * 2);
    float* gif    = (float*)alloc((size_t)S * B * H3 * 4);
    float* gib    = (float*)alloc((size_t)S * B * H3 * 4);
    float* dgi    = (float*)alloc((size_t)T * NB * H3 * 4);
    float* ysf    = (float*)alloc((size_t)B * S * H * 4);
    float* ysb    = (float*)alloc((size_t)B * S * H * 4);
    float* hfv    = (float*)alloc((size_t)B * H * 4);
    float* hbv    = (float*)alloc((size_t)B * H * 4);
    u16*   Eb     = (u16*)alloc((size_t)B * S * H * 2);
    u16*   ETb    = (u16*)alloc((size_t)B * H * S * 2);
    float* hf32   = (float*)alloc((size_t)NB * H * 4);
    u16*   hnk    = (u16*)alloc((size_t)NB * H * 2);
    u16*   hall   = (u16*)alloc((size_t)T * NB * H * 2);
    float* dgh    = (float*)alloc((size_t)NB * H3 * 4);
    float* probfT = (float*)alloc((size_t)T * NB * S * 4);
    float* swvT   = (float*)alloc((size_t)T * NB * 4);
    float* rowsumT = (float*)alloc((size_t)T * NB * 4);
    (void)ws_size; (void)in_sizes; (void)n_in; (void)out_size;

    auto launch_gemm = [&](const u16* A, const u16* Bt, const float* bias, float* C,
                           int M, int N, int K, int lda, int ldb, long long ldc,
                           long long sA, long long sB, long long sC, int nb,
                           int mode, float* rs) {
        dim3 g((M + 63) / 64, (N + 63) / 64, nb);
        gemm_bt<<<g, 256, 0, stream>>>(A, Bt, bias, C, M, N, K, lda, ldb, ldc,
                                       sA, sB, sC, mode, rs);
    };

    hipFuncSetAttribute((const void*)fused_step_kernel,
                        hipFuncAttributeMaxDynamicSharedMemorySize, FUSED_LDS);

    // ---- setup: casts, embeddings, input-side GEMMs -----------------------
    cvt_bf16_kernel<<<2048, 256, 0, stream>>>(emb, embb, V * H);
    cvt4_kernel<<<1024, 256, 0, stream>>>(wihf, wihb, dwih, dwhh,
                                          wihfb, wihbb, dwihb, dwhhb, H3 * H);
    {
        const int total = 2 * ENBLK * EROWS * EKP;
        prep_wenc_kernel<<<(total + 255) / 256, 256, 0, stream>>>(whhf, whhb, wencp);
    }
    embed_story_kernel<<<S * B, 256, 0, stream>>>(story, embb, xb);
    { dim3 g(NB, T); build_decin_kernel<<<g, 256, 0, stream>>>(tgt, dom, sidx, slt, embb, decinb); }

    launch_gemm(xb, wihfb, bihf, gif, S * B, H3, H, H, H, H3, 0, 0, 0, 1, 0, nullptr);
    launch_gemm(xb, wihbb, bihb, gib, S * B, H3, H, H, H, H3, 0, 0, 0, 1, 0, nullptr);
    launch_gemm(decinb, dwihb, dbih, dgi, T * NB, H3, H, H, H, H3, 0, 0, 0, 1, 0, nullptr);

    // ---- encoder recurrence (R8 protocol) ---------------------------------
    hipMemsetAsync(flags, 0, (size_t)2 * S * ENBLK * 4, stream);
    hipMemsetAsync(hbuf, 0, (size_t)2 * S * B * EKP * 4, stream);
    hipMemsetAsync(rowsumT, 0, (size_t)T * NB * 4, stream);
    enc_rnn2_kernel<<<2 * ENBLK, 256, 0, stream>>>(wencp, bhhf, bhhb, gif, gib, lens,
                                                   hbuf, flags, ysf, ysb, hfv, hbv);
    { dim3 g(B, S / 32); packE_kernel<<<g, 256, 0, stream>>>(ysf, ysb, Eb, ETb); }
    h0_kernel<<<NB, 256, 0, stream>>>(hfv, hbv, hf32, hnk);

    // ---- decoder: sequential chain (2 launches/step, R8 structure) --------
    for (int t = 0; t < T; ++t) {
        const u16* hprev = (t == 0) ? hnk : hall + (size_t)(t - 1) * NB * H;
        launch_gemm(hprev, dwhhb, dbhh, dgh, NB, H3, H, H, H, H3, 0, 0, 0, 1, 0, nullptr);
        fused_step_kernel<<<16, 512, FUSED_LDS, stream>>>(
            dgi, dgh, hf32, hall, decinb, Eb, ETb, lens, Wr, br, Wg, bg,
            probfT, swvT, out + (size_t)NB * T * V, t);
    }

    // ---- batched vocab projection: dedicated 128x128-tile GEMM ------------
    {
        dim3 g((MM + 127) / 128, (V + 127) / 128);
        vocab_gemm_kernel<<<g, 256, 0, stream>>>(hall, embb, out, rowsumT);
    }
    { dim3 g(NB, (V + 255) / 256); scale_all_kernel<<<g, 256, 0, stream>>>(out, swvT, rowsumT); }
    { dim3 g(NB, T); scatter_all_kernel<<<g, 256, 0, stream>>>(out, story, lens, swvT, probfT); }
}

// Round 12
// 2403.326 us; speedup vs baseline: 1.3048x; 1.0087x over previous
//
#include <hip/hip_runtime.h>
#include <hip/hip_bf16.h>

typedef unsigned short u16;
typedef __attribute__((ext_vector_type(8))) short bf16x8;
typedef __attribute__((ext_vector_type(4))) float f32x4;
typedef __attribute__((ext_vector_type(4))) unsigned u32x4;

static constexpr int V = 20000, H = 400, B = 16, S = 256, NSLOT = 30, T = 10, G = 3;
static constexpr int H3 = 3 * H;           // 1200
static constexpr int NB = NSLOT * B;       // 480
static constexpr int MM = T * NB;          // 4800 vocab-GEMM rows
// encoder partition (R8 protocol — best measured)
static constexpr int ENBLK = 20;           // blocks per direction
static constexpr int ESL   = 20;           // h components per block (400/20)
static constexpr int EROWS = 64;           // padded weight rows per block
static constexpr int EKP   = 416;          // padded K
static constexpr int ENC_BLOCKS = 2 * ENBLK;               // 40
static constexpr int DGI_TM = (MM + 63) / 64;              // 75
static constexpr int DGI_TN = (H3 + 63) / 64;              // 19
static constexpr int DGI_TILES = DGI_TM * DGI_TN;          // 1425
// fused decoder LDS strides
static constexpr int HP2 = 424;            // h_lds row stride (u16)
static constexpr int SCP = 260;            // scores row stride (f32)
static constexpr int PP  = 264;            // prob row stride (u16)
static constexpr int CXP = 404;            // ctx row stride (f32)
static constexpr int FUSED_LDS = 32*HP2*2 + 32*SCP*4 + 32*PP*2 + 32*CXP*4; // 129024
// prep_all segment sizes
static constexpr int NE = V * H;                           // 8,000,000
static constexpr int NW = H3 * H;                          // 480,000
static constexpr int NP = 2 * ENBLK * EROWS * EKP;         // 1,064,960

__device__ __forceinline__ float bf2f(u16 v) {
    union { unsigned u; float f; } x; x.u = ((unsigned)v) << 16; return x.f;
}
__device__ __forceinline__ u16 f2bf(float f) {
    union { float f; unsigned u; } x; x.f = f;
    unsigned r = x.u + 0x7fffu + ((x.u >> 16) & 1u);   // round-to-nearest-even
    return (u16)(r >> 16);
}
__device__ __forceinline__ float sigm(float v) { return 1.f / (1.f + __expf(-v)); }

// ---------------------------------------------------------------------------
// Generic GEMM (used for the per-step dgh): C[m][n] = A.Bt^T + bias
// ---------------------------------------------------------------------------
__global__ __launch_bounds__(256) void gemm_bt(
    const u16* __restrict__ A, const u16* __restrict__ Bt,
    const float* __restrict__ bias, float* __restrict__ C,
    int M, int N, int K, int lda, int ldb, long long ldc)
{
    __shared__ u16 As[64][40];
    __shared__ u16 Bs[64][40];
    const int m0 = blockIdx.x * 64, n0 = blockIdx.y * 64;
    const int tid = threadIdx.x, wave = tid >> 6, lane = tid & 63;
    const int wm = (wave >> 1) * 32, wn = (wave & 1) * 32;
    const int srow = tid >> 2, scol = (tid & 3) * 8;
    const int fr = lane & 15, kq = lane >> 4;
    f32x4 acc[2][2];
#pragma unroll
    for (int i = 0; i < 2; ++i)
#pragma unroll
        for (int j = 0; j < 2; ++j) acc[i][j] = (f32x4){0.f, 0.f, 0.f, 0.f};

    for (int k0 = 0; k0 < K; k0 += 32) {
        {
            int gr = m0 + srow, gc = k0 + scol;
            bf16x8 v;
            if (gr < M && gc + 8 <= K) {
                v = *(const bf16x8*)(A + (long long)gr * lda + gc);
            } else {
                short tmp[8];
#pragma unroll
                for (int j = 0; j < 8; ++j)
                    tmp[j] = (gr < M && gc + j < K) ? (short)A[(long long)gr * lda + gc + j] : (short)0;
                v = *(bf16x8*)tmp;
            }
            *(bf16x8*)&As[srow][scol] = v;
        }
        {
            int gr = n0 + srow, gc = k0 + scol;
            bf16x8 v;
            if (gr < N && gc + 8 <= K) {
                v = *(const bf16x8*)(Bt + (long long)gr * ldb + gc);
            } else {
                short tmp[8];
#pragma unroll
                for (int j = 0; j < 8; ++j)
                    tmp[j] = (gr < N && gc + j < K) ? (short)Bt[(long long)gr * ldb + gc + j] : (short)0;
                v = *(bf16x8*)tmp;
            }
            *(bf16x8*)&Bs[srow][scol] = v;
        }
        __syncthreads();
        bf16x8 af[2], bfr[2];
#pragma unroll
        for (int i = 0; i < 2; ++i) af[i]  = *(const bf16x8*)&As[wm + i * 16 + fr][kq * 8];
#pragma unroll
        for (int j = 0; j < 2; ++j) bfr[j] = *(const bf16x8*)&Bs[wn + j * 16 + fr][kq * 8];
#pragma unroll
        for (int i = 0; i < 2; ++i)
#pragma unroll
            for (int j = 0; j < 2; ++j)
                acc[i][j] = __builtin_amdgcn_mfma_f32_16x16x32_bf16(af[i], bfr[j], acc[i][j], 0, 0, 0);
        __syncthreads();
    }

#pragma unroll
    for (int i = 0; i < 2; ++i)
#pragma unroll
        for (int j = 0; j < 2; ++j) {
            int col = n0 + wn + j * 16 + fr;
            float bv = (bias != nullptr && col < N) ? bias[col] : 0.f;
#pragma unroll
            for (int r = 0; r < 4; ++r) {
                int row = m0 + wm + i * 16 + kq * 4 + r;
                if (row < M && col < N) C[(long long)row * ldc + col] = acc[i][j][r] + bv;
            }
        }
}

// ---------------------------------------------------------------------------
// gif + gib in ONE launch: blockIdx.z picks (W, bias, C). A = xb, M = S*B.
// ---------------------------------------------------------------------------
__global__ __launch_bounds__(256) void gemm_xw2_kernel(
    const u16* __restrict__ A,
    const u16* __restrict__ W0, const u16* __restrict__ W1,
    const float* __restrict__ b0, const float* __restrict__ b1,
    float* __restrict__ C0, float* __restrict__ C1)
{
    const int z = blockIdx.z;
    const u16* Bt = z ? W1 : W0;
    const float* bias = z ? b1 : b0;
    float* C = z ? C1 : C0;
    const int M = S * B, N = H3, K = H;

    __shared__ u16 As[64][40];
    __shared__ u16 Bs[64][40];
    const int m0 = blockIdx.x * 64, n0 = blockIdx.y * 64;
    const int tid = threadIdx.x, wave = tid >> 6, lane = tid & 63;
    const int wm = (wave >> 1) * 32, wn = (wave & 1) * 32;
    const int srow = tid >> 2, scol = (tid & 3) * 8;
    const int fr = lane & 15, kq = lane >> 4;
    f32x4 acc[2][2];
#pragma unroll
    for (int i = 0; i < 2; ++i)
#pragma unroll
        for (int j = 0; j < 2; ++j) acc[i][j] = (f32x4){0.f, 0.f, 0.f, 0.f};

    for (int k0 = 0; k0 < K; k0 += 32) {
        {
            int gr = m0 + srow, gc = k0 + scol;
            bf16x8 v = (bf16x8){0,0,0,0,0,0,0,0};
            if (gr < M && gc + 8 <= K) v = *(const bf16x8*)(A + (long long)gr * K + gc);
            *(bf16x8*)&As[srow][scol] = v;
        }
        {
            int gr = n0 + srow, gc = k0 + scol;
            bf16x8 v = (bf16x8){0,0,0,0,0,0,0,0};
            if (gr < N && gc + 8 <= K) v = *(const bf16x8*)(Bt + (long long)gr * K + gc);
            *(bf16x8*)&Bs[srow][scol] = v;
        }
        __syncthreads();
        bf16x8 af[2], bfr[2];
#pragma unroll
        for (int i = 0; i < 2; ++i) af[i]  = *(const bf16x8*)&As[wm + i * 16 + fr][kq * 8];
#pragma unroll
        for (int j = 0; j < 2; ++j) bfr[j] = *(const bf16x8*)&Bs[wn + j * 16 + fr][kq * 8];
#pragma unroll
        for (int i = 0; i < 2; ++i)
#pragma unroll
            for (int j = 0; j < 2; ++j)
                acc[i][j] = __builtin_amdgcn_mfma_f32_16x16x32_bf16(af[i], bfr[j], acc[i][j], 0, 0, 0);
        __syncthreads();
    }

#pragma unroll
    for (int i = 0; i < 2; ++i)
#pragma unroll
        for (int j = 0; j < 2; ++j) {
            int col = n0 + wn + j * 16 + fr;
            float bv = (col < N) ? bias[col] : 0.f;
#pragma unroll
            for (int r = 0; r < 4; ++r) {
                int row = m0 + wm + i * 16 + kq * 4 + r;
                if (row < M && col < N) C[(long long)row * H3 + col] = acc[i][j][r] + bv;
            }
        }
}

// ---------------------------------------------------------------------------
// Dedicated 128x128-tile vocab GEMM (R11, unchanged)
// ---------------------------------------------------------------------------
__global__ __launch_bounds__(256) void vocab_gemm_kernel(
    const u16* __restrict__ A, const u16* __restrict__ Bt,
    float* __restrict__ C, float* __restrict__ rowsum)
{
    __shared__ u16 As[128][40];
    __shared__ u16 Bs[128][40];
    const int m0 = blockIdx.x * 128, n0 = blockIdx.y * 128;
    const int tid = threadIdx.x, wave = tid >> 6, lane = tid & 63;
    const int wm = (wave >> 1) * 64, wn = (wave & 1) * 64;
    const int srow = tid >> 1, scol = (tid & 1) * 16;
    const int fr = lane & 15, kq = lane >> 4;
    f32x4 acc[4][4];
#pragma unroll
    for (int i = 0; i < 4; ++i)
#pragma unroll
        for (int j = 0; j < 4; ++j) acc[i][j] = (f32x4){0.f, 0.f, 0.f, 0.f};

    for (int k0 = 0; k0 < H; k0 += 32) {
        {
            int gr = m0 + srow, gc = k0 + scol;
            bf16x8 v0 = (bf16x8){0,0,0,0,0,0,0,0}, v1 = v0;
            if (gr < MM) {
                const u16* src = A + (long long)gr * H + gc;
                if (gc + 8 <= H)  v0 = *(const bf16x8*)src;
                if (gc + 16 <= H) v1 = *(const bf16x8*)(src + 8);
            }
            *(bf16x8*)&As[srow][scol] = v0;
            *(bf16x8*)&As[srow][scol + 8] = v1;
        }
        {
            int gr = n0 + srow, gc = k0 + scol;
            bf16x8 v0 = (bf16x8){0,0,0,0,0,0,0,0}, v1 = v0;
            if (gr < V) {
                const u16* src = Bt + (long long)gr * H + gc;
                if (gc + 8 <= H)  v0 = *(const bf16x8*)src;
                if (gc + 16 <= H) v1 = *(const bf16x8*)(src + 8);
            }
            *(bf16x8*)&Bs[srow][scol] = v0;
            *(bf16x8*)&Bs[srow][scol + 8] = v1;
        }
        __syncthreads();
        bf16x8 af[4], bfr[4];
#pragma unroll
        for (int i = 0; i < 4; ++i) af[i]  = *(const bf16x8*)&As[wm + i * 16 + fr][kq * 8];
#pragma unroll
        for (int j = 0; j < 4; ++j) bfr[j] = *(const bf16x8*)&Bs[wn + j * 16 + fr][kq * 8];
#pragma unroll
        for (int i = 0; i < 4; ++i)
#pragma unroll
            for (int j = 0; j < 4; ++j)
                acc[i][j] = __builtin_amdgcn_mfma_f32_16x16x32_bf16(af[i], bfr[j], acc[i][j], 0, 0, 0);
        __syncthreads();
    }

#pragma unroll
    for (int i = 0; i < 4; ++i)
#pragma unroll
        for (int j = 0; j < 4; ++j)
#pragma unroll
            for (int r = 0; r < 4; ++r) {
                int row = m0 + wm + i * 16 + kq * 4 + r;
                int col = n0 + wn + j * 16 + fr;
                bool ok = (row < MM) && (col < V);
                float v = ok ? __expf(acc[i][j][r]) : 0.f;
                acc[i][j][r] = v;
                if (ok) {
                    int n = row % NB, t = row / NB;
                    C[((long long)n * T + t) * V + col] = v;
                }
            }
#pragma unroll
    for (int i = 0; i < 4; ++i)
#pragma unroll
        for (int r = 0; r < 4; ++r) {
            float s = acc[i][0][r] + acc[i][1][r] + acc[i][2][r] + acc[i][3][r];
            s += __shfl_xor(s, 1); s += __shfl_xor(s, 2);
            s += __shfl_xor(s, 4); s += __shfl_xor(s, 8);
            if (fr == 0) {
                int row = m0 + wm + i * 16 + kq * 4 + r;
                if (row < MM) atomicAdd(&rowsum[row], s);
            }
        }
}

// ---------------------------------------------------------------------------
// prep_all: emb cvt + 4 weight cvts + encoder weight prep, one grid-stride
// ---------------------------------------------------------------------------
__global__ void prep_all_kernel(
    const float* __restrict__ emb, u16* __restrict__ embb,
    const float* __restrict__ wihf, u16* __restrict__ wihfb,
    const float* __restrict__ wihb, u16* __restrict__ wihbb,
    const float* __restrict__ dwih, u16* __restrict__ dwihb,
    const float* __restrict__ dwhh, u16* __restrict__ dwhhb,
    const float* __restrict__ whhf, const float* __restrict__ whhb,
    u16* __restrict__ wencp)
{
    const int total = NE + 4 * NW + NP;
    for (int i = blockIdx.x * blockDim.x + threadIdx.x; i < total;
         i += gridDim.x * blockDim.x) {
        if (i < NE) { embb[i] = f2bf(emb[i]); continue; }
        int i2 = i - NE;
        if (i2 < NW) { wihfb[i2] = f2bf(wihf[i2]); continue; }
        i2 -= NW;
        if (i2 < NW) { wihbb[i2] = f2bf(wihb[i2]); continue; }
        i2 -= NW;
        if (i2 < NW) { dwihb[i2] = f2bf(dwih[i2]); continue; }
        i2 -= NW;
        if (i2 < NW) { dwhhb[i2] = f2bf(dwhh[i2]); continue; }
        i2 -= NW;
        // encoder weight prep: dst[dir][j][rloc][k], rloc = g*20+c
        int k = i2 % EKP; int r = i2 / EKP;
        int rloc = r % EROWS; r /= EROWS;
        int j = r % ENBLK; int dir = r / ENBLK;
        u16 v = 0;
        if (k < H && rloc < 3 * ESL) {
            int g = rloc / ESL, c = rloc % ESL;
            const float* W = dir ? whhb : whhf;
            v = f2bf(W[(long long)(g * H + j * ESL + c) * H + k]);
        }
        wencp[i2] = v;
    }
}

// embed_story (rows 0..4095) + build_decin (rows 4096..8895), one launch
__global__ void embed_decin_kernel(
    const int* __restrict__ story, const u16* __restrict__ embb,
    u16* __restrict__ xb,
    const int* __restrict__ tgt, const int* __restrict__ dom,
    const int* __restrict__ sidx, const float* __restrict__ slt,
    u16* __restrict__ decin)
{
    int row = blockIdx.x;
    if (row < S * B) {
        int s = row >> 4, b = row & 15;
        int tok = story[b * S + s];
        const u16* e = embb + (long long)tok * H;
        u16* d = xb + (long long)row * H;
        for (int k = threadIdx.x; k < H; k += blockDim.x) d[k] = e[k];
    } else {
        int i = row - S * B;
        int t = i / NB, n = i % NB;
        int b = n & 15, slot = n >> 4;
        u16* d = decin + ((long long)t * NB + n) * H;
        if (t == 0) {
            const float* s1 = slt + (long long)dom[slot] * H;
            const float* s2 = slt + (long long)sidx[slot] * H;
            for (int k = threadIdx.x; k < H; k += blockDim.x) d[k] = f2bf(s1[k] + s2[k]);
        } else {
            int tok = tgt[(b * NSLOT + slot) * T + (t - 1)];
            const u16* e = embb + (long long)tok * H;
            for (int k = threadIdx.x; k < H; k += blockDim.x) d[k] = e[k];
        }
    }
}

// ---------------------------------------------------------------------------
// Combined launch: blocks 0..39 = R8-protocol encoder (verbatim);
// blocks 40.. = dgi GEMM tiles (decinb @ dwihb^T + dbih -> dgi), which run
// CONCURRENTLY on the CUs the encoder leaves idle. No inter-role deps.
// ---------------------------------------------------------------------------
__global__ __launch_bounds__(256) void enc_dgi_kernel(
    const u16* __restrict__ wencp,
    const float* __restrict__ bhhf, const float* __restrict__ bhhb,
    const float* __restrict__ gif, const float* __restrict__ gib,
    const int* __restrict__ lens,
    unsigned* __restrict__ hbuf, int* __restrict__ flags,
    float* __restrict__ ysf, float* __restrict__ ysb,
    float* __restrict__ hfo, float* __restrict__ hbo,
    const u16* __restrict__ decinb, const u16* __restrict__ dwhib,
    const float* __restrict__ dbih, float* __restrict__ dgi)
{
    __shared__ __align__(16) char ldsu[EROWS * EKP * 2 + EROWS * 17 * 4];
    const int tid = threadIdx.x, wave = tid >> 6, lane = tid & 63;
    const int fr = lane & 15, kq = lane >> 4;

    if (blockIdx.x >= ENC_BLOCKS) {
        // ---------------- dgi GEMM role (64^2 tile, mode-0) ----------------
        u16* As = (u16*)ldsu;              // [64][40]
        u16* Bs = As + 64 * 40;            // [64][40]
        const int tile = blockIdx.x - ENC_BLOCKS;
        const int m0 = (tile % DGI_TM) * 64, n0 = (tile / DGI_TM) * 64;
        const int wm = (wave >> 1) * 32, wn = (wave & 1) * 32;
        const int srow = tid >> 2, scol = (tid & 3) * 8;
        f32x4 acc[2][2];
#pragma unroll
        for (int i = 0; i < 2; ++i)
#pragma unroll
            for (int j = 0; j < 2; ++j) acc[i][j] = (f32x4){0.f, 0.f, 0.f, 0.f};

        for (int k0 = 0; k0 < H; k0 += 32) {
            {
                int gr = m0 + srow, gc = k0 + scol;
                bf16x8 v = (bf16x8){0,0,0,0,0,0,0,0};
                if (gr < MM && gc + 8 <= H) v = *(const bf16x8*)(decinb + (long long)gr * H + gc);
                *(bf16x8*)&As[srow * 40 + scol] = v;
            }
            {
                int gr = n0 + srow, gc = k0 + scol;
                bf16x8 v = (bf16x8){0,0,0,0,0,0,0,0};
                if (gr < H3 && gc + 8 <= H) v = *(const bf16x8*)(dwhib + (long long)gr * H + gc);
                *(bf16x8*)&Bs[srow * 40 + scol] = v;
            }
            __syncthreads();
            bf16x8 af[2], bfr[2];
#pragma unroll
            for (int i = 0; i < 2; ++i) af[i]  = *(const bf16x8*)&As[(wm + i * 16 + fr) * 40 + kq * 8];
#pragma unroll
            for (int j = 0; j < 2; ++j) bfr[j] = *(const bf16x8*)&Bs[(wn + j * 16 + fr) * 40 + kq * 8];
#pragma unroll
            for (int i = 0; i < 2; ++i)
#pragma unroll
                for (int j = 0; j < 2; ++j)
                    acc[i][j] = __builtin_amdgcn_mfma_f32_16x16x32_bf16(af[i], bfr[j], acc[i][j], 0, 0, 0);
            __syncthreads();
        }
#pragma unroll
        for (int i = 0; i < 2; ++i)
#pragma unroll
            for (int j = 0; j < 2; ++j) {
                int col = n0 + wn + j * 16 + fr;
                float bv = (col < H3) ? dbih[col] : 0.f;
#pragma unroll
                for (int r = 0; r < 4; ++r) {
                    int row = m0 + wm + i * 16 + kq * 4 + r;
                    if (row < MM && col < H3) dgi[(long long)row * H3 + col] = acc[i][j][r] + bv;
                }
            }
        return;
    }

    // -------------------- encoder role (R8 protocol, verbatim) -------------
    u16* wlds = (u16*)ldsu;                       // EROWS*EKP
    float* ghs = (float*)(ldsu + EROWS * EKP * 2); // EROWS*17
    const int bid = blockIdx.x;
    const int dir = bid / ENBLK, j = bid % ENBLK;
    const float* bhh = dir ? bhhb : bhhf;
    const float* gi  = dir ? gib  : gif;
    float* ys = dir ? ysb : ysf;
    float* ho = dir ? hbo : hfo;

    const u16* wsrc = wencp + (long long)(dir * ENBLK + j) * EROWS * EKP;
    for (int i = tid * 8; i < EROWS * EKP; i += 256 * 8)
        *(bf16x8*)&wlds[i] = *(const bf16x8*)&wsrc[i];
    for (int i = tid; i < EROWS * 17; i += 256) ghs[i] = 0.f;

    const int p0 = tid, p1 = 256 + tid;
    const bool has1 = (tid < 64);
    const int b0 = p0 / ESL, kl0 = p0 % ESL;
    const int b1 = has1 ? p1 / ESL : 0, kl1 = has1 ? p1 % ESL : 0;
    const int k0 = j * ESL;
    const int len0 = lens[b0];
    const int len1 = has1 ? lens[b1] : 0;
    const float bhr0 = bhh[k0 + kl0], bhz0 = bhh[H + k0 + kl0], bhn0 = bhh[2 * H + k0 + kl0];
    const float bhr1 = has1 ? bhh[k0 + kl1] : 0.f;
    const float bhz1 = has1 ? bhh[H + k0 + kl1] : 0.f;
    const float bhn1 = has1 ? bhh[2 * H + k0 + kl1] : 0.f;
    float h0r = 0.f, h1r = 0.f;

    unsigned* hb_d = hbuf + (long long)dir * S * B * EKP;
    int* flg_d = flags + dir * S * ENBLK;
    const u16* arow = &wlds[(wave * 16 + fr) * EKP + kq * 8];
    __syncthreads();

    for (int t = 0; t < S; ++t) {
        const int s = dir ? (S - 1 - t) : t;
        const float* gbase = gi + (long long)s * B * H3;
        float gr0 = gbase[b0 * H3 + k0 + kl0];
        float gz0 = gbase[b0 * H3 + H + k0 + kl0];
        float gn0 = gbase[b0 * H3 + 2 * H + k0 + kl0];
        float gr1 = 0.f, gz1 = 0.f, gn1 = 0.f;
        if (has1) {
            gr1 = gbase[b1 * H3 + k0 + kl1];
            gz1 = gbase[b1 * H3 + H + k0 + kl1];
            gn1 = gbase[b1 * H3 + 2 * H + k0 + kl1];
        }

        f32x4 acc = (f32x4){0.f, 0.f, 0.f, 0.f};
        if (t > 0) {
            const int* fl = flg_d + (t - 1) * ENBLK;
            for (;;) {
                int v = 1;
                if (lane < ENBLK)
                    v = __hip_atomic_load(&fl[lane], __ATOMIC_RELAXED,
                                          __HIP_MEMORY_SCOPE_AGENT);
                if (__all(v != 0)) break;
                __builtin_amdgcn_s_sleep(2);
            }
            asm volatile("" ::: "memory");   // keep hbuf reads after the poll
            const unsigned* hrow = hb_d + ((long long)(t - 1) * B + fr) * EKP + kq * 8;
            f32x4 acch = (f32x4){0.f, 0.f, 0.f, 0.f};
            f32x4 accl = (f32x4){0.f, 0.f, 0.f, 0.f};
#pragma unroll
            for (int kk = 0; kk < 13; ++kk) {
                u32x4 a = *(const u32x4*)(hrow + kk * 32);
                u32x4 b = *(const u32x4*)(hrow + kk * 32 + 4);
                union { unsigned u[4]; bf16x8 v; } hi, lo;
                hi.u[0] = __builtin_amdgcn_perm(a[1], a[0], 0x05040100u);
                hi.u[1] = __builtin_amdgcn_perm(a[3], a[2], 0x05040100u);
                hi.u[2] = __builtin_amdgcn_perm(b[1], b[0], 0x05040100u);
                hi.u[3] = __builtin_amdgcn_perm(b[3], b[2], 0x05040100u);
                lo.u[0] = __builtin_amdgcn_perm(a[1], a[0], 0x07060302u);
                lo.u[1] = __builtin_amdgcn_perm(a[3], a[2], 0x07060302u);
                lo.u[2] = __builtin_amdgcn_perm(b[1], b[0], 0x07060302u);
                lo.u[3] = __builtin_amdgcn_perm(b[3], b[2], 0x07060302u);
                bf16x8 av = *(const bf16x8*)(arow + kk * 32);
                acch = __builtin_amdgcn_mfma_f32_16x16x32_bf16(av, hi.v, acch, 0, 0, 0);
                accl = __builtin_amdgcn_mfma_f32_16x16x32_bf16(av, lo.v, accl, 0, 0, 0);
            }
            acc = acch + accl;
        }
#pragma unroll
        for (int r = 0; r < 4; ++r) ghs[(wave * 16 + kq * 4 + r) * 17 + fr] = acc[r];
        __syncthreads();

        unsigned* hpub = hb_d + (long long)t * B * EKP;
        {
            float ghr = ghs[kl0 * 17 + b0];
            float ghz = ghs[(ESL + kl0) * 17 + b0];
            float ghn = ghs[(2 * ESL + kl0) * 17 + b0];
            float rg = sigm(gr0 + ghr + bhr0);
            float zg = sigm(gz0 + ghz + bhz0);
            float ng = tanhf(gn0 + rg * (ghn + bhn0));
            float hn = (1.f - zg) * ng + zg * h0r;
            bool msk = s < len0;
            float y = msk ? hn : 0.f;
            if (msk) h0r = hn;
            ys[((long long)(b0 * S + s)) * H + k0 + kl0] = y;
            u16 hi = f2bf(h0r);
            unsigned packed = (unsigned)hi | ((unsigned)f2bf(h0r - bf2f(hi)) << 16);
            __hip_atomic_store(&hpub[b0 * EKP + k0 + kl0], packed, __ATOMIC_RELAXED,
                               __HIP_MEMORY_SCOPE_AGENT);
        }
        if (has1) {
            float ghr = ghs[kl1 * 17 + b1];
            float ghz = ghs[(ESL + kl1) * 17 + b1];
            float ghn = ghs[(2 * ESL + kl1) * 17 + b1];
            float rg = sigm(gr1 + ghr + bhr1);
            float zg = sigm(gz1 + ghz + bhz1);
            float ng = tanhf(gn1 + rg * (ghn + bhn1));
            float hn = (1.f - zg) * ng + zg * h1r;
            bool msk = s < len1;
            float y = msk ? hn : 0.f;
            if (msk) h1r = hn;
            ys[((long long)(b1 * S + s)) * H + k0 + kl1] = y;
            u16 hi = f2bf(h1r);
            unsigned packed = (unsigned)hi | ((unsigned)f2bf(h1r - bf2f(hi)) << 16);
            __hip_atomic_store(&hpub[b1 * EKP + k0 + kl1], packed, __ATOMIC_RELAXED,
                               __HIP_MEMORY_SCOPE_AGENT);
        }
        __syncthreads();
        if (tid == 0)
            __hip_atomic_store(&flg_d[t * ENBLK + j], 1, __ATOMIC_RELAXED,
                               __HIP_MEMORY_SCOPE_AGENT);
    }
    ho[b0 * H + k0 + kl0] = h0r;
    if (has1) ho[b1 * H + k0 + kl1] = h1r;
}

// E = ys_f + ys_b (bf16, [b][s][k]) and ET (bf16, [b][k][s])
__global__ void packE_kernel(const float* __restrict__ ysf, const float* __restrict__ ysb,
                             u16* __restrict__ E, u16* __restrict__ ET) {
    __shared__ u16 tile[32][400];
    const int b = blockIdx.x, s0 = blockIdx.y * 32;
    for (int si = 0; si < 32; ++si) {
        const long long base = ((long long)b * S + s0 + si) * H;
        for (int k = threadIdx.x; k < H; k += blockDim.x) {
            u16 v = f2bf(ysf[base + k] + ysb[base + k]);
            E[base + k] = v;
            tile[si][k] = v;
        }
    }
    __syncthreads();
    for (int idx = threadIdx.x; idx < 32 * H; idx += blockDim.x) {
        int k = idx >> 5, si = idx & 31;
        ET[((long long)b * H + k) * S + s0 + si] = tile[si][k];
    }
}

__global__ void h0_kernel(const float* __restrict__ hf, const float* __restrict__ hb,
                          float* __restrict__ hf32, u16* __restrict__ hnk) {
    int n = blockIdx.x, b = n & 15;
    for (int k = threadIdx.x; k < H; k += blockDim.x) {
        float v = hf[b * H + k] + hb[b * H + k];
        hf32[(long long)n * H + k] = v;
        hnk[(long long)n * H + k] = f2bf(v);
    }
}

// ---------------------------------------------------------------------------
// Fused decoder step (R8 version): block = batch b (16 blocks, 512 threads).
// ---------------------------------------------------------------------------
__global__ __launch_bounds__(512) void fused_step_kernel(
    const float* __restrict__ dgi, const float* __restrict__ dgh,
    float* __restrict__ hf32, u16* __restrict__ hall,
    const u16* __restrict__ decinb,
    const u16* __restrict__ Eb, const u16* __restrict__ ETb,
    const int* __restrict__ lens,
    const float* __restrict__ Wr, const float* __restrict__ br,
    const float* __restrict__ Wg, const float* __restrict__ bg,
    float* __restrict__ probfT, float* __restrict__ swvT,
    float* __restrict__ gout, int t)
{
    extern __shared__ char smem[];
    u16*   hls = (u16*)smem;                                   // [32][HP2]
    float* scs = (float*)(smem + 32 * HP2 * 2);                // [32][SCP]
    u16*   pls = (u16*)(smem + 32 * HP2 * 2 + 32 * SCP * 4);   // [32][PP]
    float* cxs = (float*)(smem + 32 * HP2 * 2 + 32 * SCP * 4 + 32 * PP * 2); // [32][CXP]

    const int b = blockIdx.x;
    const int tid = threadIdx.x, wave = tid >> 6, lane = tid & 63;
    const int fr = lane & 15, kq = lane >> 4;
    const int len = lens[b];

    for (int i = tid; i < 32 * (HP2 - H); i += 512) {
        int r = i / (HP2 - H), c = H + i % (HP2 - H);
        hls[r * HP2 + c] = 0;
    }
    for (int i = tid; i < 2 * HP2; i += 512) hls[30 * HP2 + i] = 0;
    for (int i = tid; i < 2 * PP; i += 512) pls[30 * PP + i] = 0;

    // P0: GRU cell for the 30 slots of this batch
    for (int i = tid; i < 30 * H; i += 512) {
        int slot = i / H, k = i % H;
        int n = slot * 16 + b;
        const float* gi = dgi + ((long long)t * NB + n) * H3;
        const float* gh = dgh + (long long)n * H3;
        float r  = sigm(gi[k] + gh[k]);
        float z  = sigm(gi[H + k] + gh[H + k]);
        float nn = tanhf(gi[2 * H + k] + r * gh[2 * H + k]);
        float h  = hf32[(long long)n * H + k];
        float hn = (1.f - z) * nn + z * h;
        hf32[(long long)n * H + k] = hn;
        u16 hb = f2bf(hn);
        hall[((long long)t * NB + n) * H + k] = hb;
        hls[slot * HP2 + k] = hb;
    }
    __syncthreads();

    // P1: scores[slot][s] = h . E[b][s]   (M=32, N=256, K=400)
    {
        const int nt0 = wave * 2;
        f32x4 acc[2][2];
#pragma unroll
        for (int i = 0; i < 2; ++i)
#pragma unroll
            for (int jj = 0; jj < 2; ++jj) acc[i][jj] = (f32x4){0.f, 0.f, 0.f, 0.f};
        const u16* br0 = Eb + ((long long)b * S + nt0 * 16 + fr) * H + kq * 8;
        const u16* br1 = Eb + ((long long)b * S + (nt0 + 1) * 16 + fr) * H + kq * 8;
        const u16* ar0 = hls + fr * HP2 + kq * 8;
        const u16* ar1 = hls + (16 + fr) * HP2 + kq * 8;
#pragma unroll
        for (int kk = 0; kk < 13; ++kk) {
            bf16x8 av0 = *(const bf16x8*)(ar0 + kk * 32);
            bf16x8 av1 = *(const bf16x8*)(ar1 + kk * 32);
            bf16x8 bv0, bv1;
            if (kk == 12 && kq >= 2) {
                bv0 = (bf16x8){0,0,0,0,0,0,0,0}; bv1 = bv0;
            } else {
                bv0 = *(const bf16x8*)(br0 + kk * 32);
                bv1 = *(const bf16x8*)(br1 + kk * 32);
            }
            acc[0][0] = __builtin_amdgcn_mfma_f32_16x16x32_bf16(av0, bv0, acc[0][0], 0, 0, 0);
            acc[1][0] = __builtin_amdgcn_mfma_f32_16x16x32_bf16(av1, bv0, acc[1][0], 0, 0, 0);
            acc[0][1] = __builtin_amdgcn_mfma_f32_16x16x32_bf16(av0, bv1, acc[0][1], 0, 0, 0);
            acc[1][1] = __builtin_amdgcn_mfma_f32_16x16x32_bf16(av1, bv1, acc[1][1], 0, 0, 0);
        }
#pragma unroll
        for (int i = 0; i < 2; ++i)
#pragma unroll
            for (int jj = 0; jj < 2; ++jj)
#pragma unroll
                for (int r = 0; r < 4; ++r)
                    scs[(i * 16 + kq * 4 + r) * SCP + (nt0 + jj) * 16 + fr] = acc[i][jj][r];
    }
    __syncthreads();

    // P2: softmax rows
    for (int i = 0; i < 4; ++i) {
        int row = wave * 4 + i;
        if (row >= 30) break;
        int n = row * 16 + b;
        float v[4];
        float mx = -3.0e38f;
#pragma unroll
        for (int q = 0; q < 4; ++q) {
            int s = lane + 64 * q;
            float x = (s < len) ? scs[row * SCP + s] : -3.0e38f;
            v[q] = x; mx = fmaxf(mx, x);
        }
        mx = fmaxf(mx, __shfl_xor(mx, 1));  mx = fmaxf(mx, __shfl_xor(mx, 2));
        mx = fmaxf(mx, __shfl_xor(mx, 4));  mx = fmaxf(mx, __shfl_xor(mx, 8));
        mx = fmaxf(mx, __shfl_xor(mx, 16)); mx = fmaxf(mx, __shfl_xor(mx, 32));
        float sum = 0.f;
#pragma unroll
        for (int q = 0; q < 4; ++q) {
            int s = lane + 64 * q;
            float e = (s < len) ? __expf(v[q] - mx) : 0.f;
            v[q] = e; sum += e;
        }
        sum += __shfl_xor(sum, 1);  sum += __shfl_xor(sum, 2);
        sum += __shfl_xor(sum, 4);  sum += __shfl_xor(sum, 8);
        sum += __shfl_xor(sum, 16); sum += __shfl_xor(sum, 32);
        float inv = 1.f / sum;
#pragma unroll
        for (int q = 0; q < 4; ++q) {
            int s = lane + 64 * q;
            float pr = v[q] * inv;
            pls[row * PP + s] = f2bf(pr);
            probfT[((long long)(t * NB + n)) * S + s] = pr;
        }
    }
    __syncthreads();

    // P3: ctx[slot][k] = sum_s prob[slot][s] * ET[b][k][s]
    for (int nt = wave; nt < 25; nt += 8) {
        f32x4 acc0 = (f32x4){0.f,0.f,0.f,0.f}, acc1 = (f32x4){0.f,0.f,0.f,0.f};
        const u16* brow = ETb + ((long long)b * H + nt * 16 + fr) * S + kq * 8;
        const u16* ar0 = pls + fr * PP + kq * 8;
        const u16* ar1 = pls + (16 + fr) * PP + kq * 8;
#pragma unroll
        for (int kk = 0; kk < 8; ++kk) {
            bf16x8 bv  = *(const bf16x8*)(brow + kk * 32);
            bf16x8 av0 = *(const bf16x8*)(ar0 + kk * 32);
            bf16x8 av1 = *(const bf16x8*)(ar1 + kk * 32);
            acc0 = __builtin_amdgcn_mfma_f32_16x16x32_bf16(av0, bv, acc0, 0, 0, 0);
            acc1 = __builtin_amdgcn_mfma_f32_16x16x32_bf16(av1, bv, acc1, 0, 0, 0);
        }
#pragma unroll
        for (int r = 0; r < 4; ++r) {
            cxs[(kq * 4 + r) * CXP + nt * 16 + fr] = acc0[r];
            cxs[(16 + kq * 4 + r) * CXP + nt * 16 + fr] = acc1[r];
        }
    }
    __syncthreads();

    // P4: p_gen switch (+ gate at t==0)
    for (int i = 0; i < 4; ++i) {
        int slot = wave + 8 * i;
        if (slot >= 30) break;
        int n = slot * 16 + b;
        const u16* xrow = decinb + ((long long)t * NB + n) * H;
        float p = 0.f;
        for (int k = lane; k < H; k += 64)
            p += bf2f(hls[slot * HP2 + k]) * Wr[k]
               + cxs[slot * CXP + k] * Wr[H + k]
               + bf2f(xrow[k]) * Wr[2 * H + k];
        p += __shfl_xor(p, 1);  p += __shfl_xor(p, 2);
        p += __shfl_xor(p, 4);  p += __shfl_xor(p, 8);
        p += __shfl_xor(p, 16); p += __shfl_xor(p, 32);
        if (lane == 0) swvT[t * NB + n] = sigm(p + br[0]);
        if (t == 0) {
            for (int g = 0; g < G; ++g) {
                float q = 0.f;
                for (int k = lane; k < H; k += 64)
                    q += cxs[slot * CXP + k] * Wg[g * H + k];
                q += __shfl_xor(q, 1);  q += __shfl_xor(q, 2);
                q += __shfl_xor(q, 4);  q += __shfl_xor(q, 8);
                q += __shfl_xor(q, 16); q += __shfl_xor(q, 32);
                if (lane == 0) gout[(long long)n * G + g] = q + bg[g];
            }
        }
    }
}

// scale all t at once: out[n][t][:] *= sw[t][n] / rowsum[t*NB+n]
__global__ void scale_all_kernel(float* __restrict__ out, const float* __restrict__ swvT,
                                 const float* __restrict__ rowsumT) {
    const int n = blockIdx.x;
    const int col = blockIdx.y * 256 + threadIdx.x;
    if (col >= V) return;
#pragma unroll
    for (int t = 0; t < T; ++t) {
        float f = swvT[t * NB + n] / rowsumT[t * NB + n];
        out[((long long)n * T + t) * V + col] *= f;
    }
}

__global__ void scatter_all_kernel(float* __restrict__ out, const int* __restrict__ story,
                                   const int* __restrict__ lens, const float* __restrict__ swvT,
                                   const float* __restrict__ probfT) {
    const int n = blockIdx.x, t = blockIdx.y, b = n & 15, s = threadIdx.x;
    if (s < lens[b]) {
        int tok = story[b * S + s];
        atomicAdd(out + ((long long)n * T + t) * V + tok,
                  (1.f - swvT[t * NB + n]) * probfT[((long long)(t * NB + n)) * S + s]);
    }
}

// ---------------------------------------------------------------------------
extern "C" void kernel_launch(void* const* d_in, const int* in_sizes, int n_in,
                              void* d_out, int out_size, void* d_ws, size_t ws_size,
                              hipStream_t stream) {
    const int*   story = (const int*)d_in[0];
    const int*   lens  = (const int*)d_in[1];
    const int*   tgt   = (const int*)d_in[2];
    const int*   dom   = (const int*)d_in[3];
    const int*   sidx  = (const int*)d_in[4];
    const float* emb   = (const float*)d_in[5];
    const float* wihf  = (const float*)d_in[6];
    const float* whhf  = (const float*)d_in[7];
    const float* bihf  = (const float*)d_in[8];
    const float* bhhf  = (const float*)d_in[9];
    const float* wihb  = (const float*)d_in[10];
    const float* whhb  = (const float*)d_in[11];
    const float* bihb  = (const float*)d_in[12];
    const float* bhhb  = (const float*)d_in[13];
    const float* dwih  = (const float*)d_in[14];
    const float* dwhh  = (const float*)d_in[15];
    const float* dbih  = (const float*)d_in[16];
    const float* dbhh  = (const float*)d_in[17];
    const float* Wr    = (const float*)d_in[18];
    const float* br    = (const float*)d_in[19];
    const float* Wg    = (const float*)d_in[20];
    const float* bg    = (const float*)d_in[21];
    const float* slt   = (const float*)d_in[22];
    float* out = (float*)d_out;

    char* wsb = (char*)d_ws;
    size_t off = 0;
    auto alloc = [&](size_t bytes) -> char* {
        char* p = wsb + off;
        off += (bytes + 255) & ~(size_t)255;
        return p;
    };
    u16*   embb   = (u16*)alloc((size_t)V * H * 2);
    u16*   wihfb  = (u16*)alloc((size_t)H3 * H * 2);
    u16*   wihbb  = (u16*)alloc((size_t)H3 * H * 2);
    u16*   dwihb  = (u16*)alloc((size_t)H3 * H * 2);
    u16*   dwhhb  = (u16*)alloc((size_t)H3 * H * 2);
    u16*   wencp  = (u16*)alloc((size_t)2 * ENBLK * EROWS * EKP * 2);
    unsigned* hbuf = (unsigned*)alloc((size_t)2 * S * B * EKP * 4);   // 13.6 MB rotating
    int*   flags  = (int*)alloc((size_t)2 * S * ENBLK * 4);           // 40 KB rotating
    u16*   xb     = (u16*)alloc((size_t)S * B * H * 2);
    u16*   decinb = (u16*)alloc((size_t)T * NB * H * 2);
    float* gif    = (float*)alloc((size_t)S * B * H3 * 4);
    float* gib    = (float*)alloc((size_t)S * B * H3 * 4);
    float* dgi    = (float*)alloc((size_t)T * NB * H3 * 4);
    float* ysf    = (float*)alloc((size_t)B * S * H * 4);
    float* ysb    = (float*)alloc((size_t)B * S * H * 4);
    float* hfv    = (float*)alloc((size_t)B * H * 4);
    float* hbv    = (float*)alloc((size_t)B * H * 4);
    u16*   Eb     = (u16*)alloc((size_t)B * S * H * 2);
    u16*   ETb    = (u16*)alloc((size_t)B * H * S * 2);
    float* hf32   = (float*)alloc((size_t)NB * H * 4);
    u16*   hnk    = (u16*)alloc((size_t)NB * H * 2);
    u16*   hall   = (u16*)alloc((size_t)T * NB * H * 2);
    float* dgh    = (float*)alloc((size_t)NB * H3 * 4);
    float* probfT = (float*)alloc((size_t)T * NB * S * 4);
    float* swvT   = (float*)alloc((size_t)T * NB * 4);
    float* rowsumT = (float*)alloc((size_t)T * NB * 4);
    (void)ws_size; (void)in_sizes; (void)n_in; (void)out_size;

    hipFuncSetAttribute((const void*)fused_step_kernel,
                        hipFuncAttributeMaxDynamicSharedMemorySize, FUSED_LDS);

    // ---- setup: fused prep + embed/decin + gif/gib GEMM -------------------
    hipMemsetAsync(flags, 0, (size_t)2 * S * ENBLK * 4, stream);
    hipMemsetAsync(hbuf, 0, (size_t)2 * S * B * EKP * 4, stream);
    hipMemsetAsync(rowsumT, 0, (size_t)T * NB * 4, stream);
    prep_all_kernel<<<2048, 256, 0, stream>>>(emb, embb, wihf, wihfb, wihb, wihbb,
                                              dwih, dwihb, dwhh, dwhhb,
                                              whhf, whhb, wencp);
    embed_decin_kernel<<<S * B + T * NB, 256, 0, stream>>>(
        story, embb, xb, tgt, dom, sidx, slt, decinb);
    {
        dim3 g((S * B + 63) / 64, (H3 + 63) / 64, 2);
        gemm_xw2_kernel<<<g, 256, 0, stream>>>(xb, wihfb, wihbb, bihf, bihb, gif, gib);
    }

    // ---- encoder recurrence + concurrent dgi GEMM (one launch) ------------
    enc_dgi_kernel<<<ENC_BLOCKS + DGI_TILES, 256, 0, stream>>>(
        wencp, bhhf, bhhb, gif, gib, lens, hbuf, flags, ysf, ysb, hfv, hbv,
        decinb, dwihb, dbih, dgi);
    { dim3 g(B, S / 32); packE_kernel<<<g, 256, 0, stream>>>(ysf, ysb, Eb, ETb); }
    h0_kernel<<<NB, 256, 0, stream>>>(hfv, hbv, hf32, hnk);

    // ---- decoder: sequential chain (2 launches/step, R8 structure) --------
    for (int t = 0; t < T; ++t) {
        const u16* hprev = (t == 0) ? hnk : hall + (size_t)(t - 1) * NB * H;
        {
            dim3 g((NB + 63) / 64, (H3 + 63) / 64);
            gemm_bt<<<g, 256, 0, stream>>>(hprev, dwhhb, dbhh, dgh,
                                           NB, H3, H, H, H, H3);
        }
        fused_step_kernel<<<16, 512, FUSED_LDS, stream>>>(
            dgi, dgh, hf32, hall, decinb, Eb, ETb, lens, Wr, br, Wg, bg,
            probfT, swvT, out + (size_t)NB * T * V, t);
    }

    // ---- batched vocab projection: dedicated 128x128-tile GEMM ------------
    {
        dim3 g((MM + 127) / 128, (V + 127) / 128);
        vocab_gemm_kernel<<<g, 256, 0, stream>>>(hall, embb, out, rowsumT);
    }
    { dim3 g(NB, (V + 255) / 256); scale_all_kernel<<<g, 256, 0, stream>>>(out, swvT, rowsumT); }
    { dim3 g(NB, T); scatter_all_kernel<<<g, 256, 0, stream>>>(out, story, lens, swvT, probfT); }
}